// Round 12
// baseline (348.960 us; speedup 1.0000x reference)
//
#include <hip/hip_runtime.h>
#include <hip/hip_bf16.h>
#include <math.h>

#define DEV __device__ __forceinline__

constexpr int B  = 8,  N = 16, P = 128, PL = 16;
constexpr int D  = 128, DS = 16, DTR = 8, DFF = 256, EL = 2;
constexpr int L  = N * P + 1;            // 2049
constexpr int BL = B * L;                // 16392
constexpr int CT = 32;                   // scan chunk length (32: verified best)
constexpr int NC = (L + CT - 1) / CT;    // 65
constexpr int MT64  = (BL + 63) / 64;    // 257
constexpr int MT32  = (BL + 31) / 32;    // 513
constexpr int KS = 136;                  // LDS row stride (bf16/short units)
constexpr int HS = 264;                  // LDS row stride for H (256+8)
constexpr int PREP_BLOCKS  = 1872;
constexpr int EMBED_BLOCKS = (BL * D + 255) / 256;  // 8196

using bf16x8 = __attribute__((ext_vector_type(8))) __bf16;
using f32x4  = __attribute__((ext_vector_type(4))) float;

DEV float sigmoidf_(float x) { return 1.0f / (1.0f + __expf(-x)); }

// r^(n+1) for n=0..15, depth-4 tree
DEV void pow_tree(float r, float* pw) {
  float r2 = r * r;
  float r3 = r2 * r;
  float r4 = r2 * r2;
  float r8 = r4 * r4;
  float r12 = r8 * r4;
  pw[0] = r;       pw[1] = r2;      pw[2] = r3;      pw[3] = r4;
  pw[4] = r4 * r;  pw[5] = r4 * r2; pw[6] = r4 * r3; pw[7] = r8;
  pw[8] = r8 * r;  pw[9] = r8 * r2; pw[10] = r8 * r3; pw[11] = r12;
  pw[12] = r12 * r; pw[13] = r12 * r2; pw[14] = r12 * r3; pw[15] = r12 * r4;
}

// A_n check: A_init = log(1..16) broadcast -> A_n = -(n+1) exactly.
DEV bool an_is_linear(const float* An) {
  bool ok = true;
#pragma unroll
  for (int n = 0; n < DS; ++n)
    ok = ok && (fabsf(An[n] + (float)(n + 1)) < 1e-3f * (n + 1));
  return ok;
}

// ---------------- merged init: weight prep (blocks 0..1871) + patch embed ----------------
__global__ __launch_bounds__(256) void k_init(
    const float* __restrict__ in_w, const float* __restrict__ conv_w,
    const float* __restrict__ xproj, const float* __restrict__ out_w,
    const float* __restrict__ w1, const float* __restrict__ w2,
    __bf16* __restrict__ weff, __bf16* __restrict__ xpw_bf,
    __bf16* __restrict__ outw_bf, __bf16* __restrict__ w1_bf,
    __bf16* __restrict__ w2_bf,
    const float* __restrict__ x, const float* __restrict__ view,
    const float* __restrict__ wp_w, const float* __restrict__ wp_b,
    float* __restrict__ U, __bf16* __restrict__ Ubf)
{
  int bid = blockIdx.x;
  if (bid < PREP_BLOCKS) {
    int g = bid * 256 + threadIdx.x;
    if (g < 262144) {
      int l = g >> 17;
      int r = g & 131071;
      int dir = r >> 16;
      int r2 = r & 65535;
      int col = r2 >> 8;
      int kk = r2 & 255;
      int chunk = kk >> 7, k = kk & 127;
      int ld = l * 2 + dir;
      float v;
      if (col < 128) {
        v = in_w[((size_t)ld * 256 + col) * 128 + k] *
            conv_w[((size_t)ld * 128 + col) * 2 + chunk];
      } else {
        v = chunk ? in_w[((size_t)ld * 256 + col) * 128 + k] : 0.f;
      }
      weff[((size_t)ld * 256 + col) * 256 + chunk * 128 + k] = (__bf16)v;
      return;
    }
    g -= 262144;
    if (g < 20480) { xpw_bf[g] = (__bf16)xproj[g]; return; }
    g -= 20480;
    if (g < 65536) {
      int k = g & 127; int q = g >> 7; int n = q & 127; int q2 = q >> 7;
      int dir = q2 & 1; int l = q2 >> 1;
      outw_bf[((size_t)(l * 128 + n)) * 256 + dir * 128 + k] = (__bf16)out_w[g];
      return;
    }
    g -= 65536;
    if (g < 65536) { w1_bf[g] = (__bf16)w1[g]; return; }
    g -= 65536;
    if (g < 65536) { w2_bf[g] = (__bf16)w2[g]; return; }
    return;
  }
  // embed part
  int g = (bid - PREP_BLOCKS) * 256 + threadIdx.x;
  if (g >= BL * D) return;
  int d = g & (D - 1);
  int row = g >> 7;
  int b = row / L, t = row % L;
  float acc;
  if (t < N * P) {
    const float* xr = x + ((size_t)b * N * P + t) * PL;
    acc = wp_b[d];
#pragma unroll
    for (int k = 0; k < PL; ++k) acc += xr[k] * wp_w[d * PL + k];
  } else {
    acc = view[b * D + d];
  }
  U[(size_t)row * D + d] = acc;
  Ubf[(size_t)row * D + d] = (__bf16)acc;
}

// ---------------- fused front: xz GEMM + conv + silu + xproj + dt ----------------
// Staging loops batched (round-5). dt softplus uses fast __logf (round-10).
// W panels register-prefetched at kernel start (round-11).
__global__ __launch_bounds__(256) void k_front(
    const __bf16* __restrict__ Ubf, const __bf16* __restrict__ Weff,
    const float* __restrict__ conv_b_l, const __bf16* __restrict__ xpw,
    const float* __restrict__ dt_w_l, const float* __restrict__ dt_b_l,
    __bf16* __restrict__ XCCbf, __bf16* __restrict__ Zbf,
    float* __restrict__ BCb, __bf16* __restrict__ DTbf)
{
  __shared__ short As[64 * KS];    // 17408 B : U staging -> later xc bf16
  __shared__ short Ws[64 * KS];    // 17408 B : weight staging
  __shared__ float dbs[64][9];     //  2304 B
  int bx = blockIdx.x;
  int rdir = bx / MT64;
  int tile = bx % MT64;
  bool isx = (blockIdx.y == 0);
  int tid = threadIdx.x;
  int m0 = tile * 64;
  const __bf16* Wb = Weff + (size_t)rdir * 256 * 256;
  int wave = tid >> 6, lane = tid & 63, lm = lane & 15, lq = lane >> 4;
  int rr0 = tid >> 4, gcol = tid & 15;
  int kc0 = isx ? 0 : 1;
  int colx = isx ? 0 : 128;

  // ---- prefetch W panels into regs (phase pidx = (kc-kc0)*2+ch) ----
  int4 wpA[4], wpB[4], wpC[4], wpD[4];
#pragma unroll
  for (int j = 0; j < 4; ++j)
    wpA[j] = *(const int4*)(Wb + (size_t)(colx + 0 * 64 + rr0 + 16 * j) * 256 + kc0 * 128 + gcol * 8);
#pragma unroll
  for (int j = 0; j < 4; ++j)
    wpB[j] = *(const int4*)(Wb + (size_t)(colx + 1 * 64 + rr0 + 16 * j) * 256 + kc0 * 128 + gcol * 8);
  if (isx) {
#pragma unroll
    for (int j = 0; j < 4; ++j)
      wpC[j] = *(const int4*)(Wb + (size_t)(colx + 0 * 64 + rr0 + 16 * j) * 256 + 128 + gcol * 8);
#pragma unroll
    for (int j = 0; j < 4; ++j)
      wpD[j] = *(const int4*)(Wb + (size_t)(colx + 1 * 64 + rr0 + 16 * j) * 256 + 128 + gcol * 8);
  }

  // per-thread A-row precompute (4 rows, one 16B column-group each)
  int aoff[4];
  unsigned vmask = 0, smask = 0;
  int shif = rdir ? 128 : -128;     // element delta for kc=0 (shifted row)
#pragma unroll
  for (int i = 0; i < 4; ++i) {
    int rr = rr0 + 16 * i;
    int m = m0 + rr;
    aoff[i] = 0;
    if (m < BL) {
      int b = m / L, s = m - b * L;
      int idx1 = rdir ? (L - 1 - s) : s;
      aoff[i] = (b * L + idx1) * 128 + gcol * 8;
      vmask |= 1u << i;
      if (s >= 1) smask |= 1u << i;
    }
  }

  f32x4 zero4 = {0.f, 0.f, 0.f, 0.f};
  f32x4 acc[8];
#pragma unroll
  for (int c = 0; c < 8; ++c) acc[c] = zero4;

  for (int kc = kc0; kc < 2; ++kc) {
    if (kc != kc0) __syncthreads();
    // stage A (64 rows): batch loads -> writes
    {
      int4 av[4];
#pragma unroll
      for (int i = 0; i < 4; ++i) {
        av[i] = make_int4(0, 0, 0, 0);
        bool ok = (vmask >> i) & 1;
        if (kc == 0) ok = ok && ((smask >> i) & 1);
        if (ok) av[i] = *(const int4*)(Ubf + aoff[i] + (kc == 0 ? shif : 0));
      }
#pragma unroll
      for (int i = 0; i < 4; ++i)
        *(int4*)&As[(rr0 + 16 * i) * KS + gcol * 8] = av[i];
    }
    for (int ch = 0; ch < 2; ++ch) {
      if (ch) __syncthreads();
      {
        int pidx = (kc - kc0) * 2 + ch;
#pragma unroll
        for (int i = 0; i < 4; ++i) {
          int4 wv = (pidx == 0) ? wpA[i] : (pidx == 1) ? wpB[i] : (pidx == 2) ? wpC[i] : wpD[i];
          *(int4*)&Ws[(rr0 + 16 * i) * KS + gcol * 8] = wv;
        }
      }
      __syncthreads();
      for (int ks = 0; ks < 128; ks += 32) {
        bf16x8 af = *(const bf16x8*)&As[(wave * 16 + lm) * KS + ks + lq * 8];
#pragma unroll
        for (int c = 0; c < 4; ++c) {
          bf16x8 bfr = *(const bf16x8*)&Ws[(c * 16 + lm) * KS + ks + lq * 8];
          acc[ch * 4 + c] = __builtin_amdgcn_mfma_f32_16x16x32_bf16(af, bfr, acc[ch * 4 + c], 0, 0, 0);
        }
      }
    }
  }

  if (!isx) {
    // z epilogue: direct scatter stores
#pragma unroll
    for (int cg = 0; cg < 8; ++cg) {
      int col = cg * 16 + lm;
#pragma unroll
      for (int e = 0; e < 4; ++e) {
        int m = m0 + wave * 16 + lq * 4 + e;
        if (m < BL)
          Zbf[((size_t)rdir * BL + m) * 128 + col] = (__bf16)acc[cg][e];
      }
    }
    return;
  }

  // x epilogue: conv bias + silu -> scatter XCC store + xc bf16 into As (wave-private rows)
  __syncthreads();   // all MFMA reads of As/Ws done
#pragma unroll
  for (int cg = 0; cg < 8; ++cg) {
    int col = cg * 16 + lm;
    float cb = conv_b_l[rdir * 128 + col];
#pragma unroll
    for (int e = 0; e < 4; ++e) {
      int rl = wave * 16 + lq * 4 + e;
      int m = m0 + rl;
      float v = acc[cg][e] + cb;
      float o = v * sigmoidf_(v);
      __bf16 ob = (__bf16)o;
      if (m < BL) XCCbf[((size_t)rdir * BL + m) * 128 + col] = ob;
      As[rl * KS + col] = (short)__builtin_bit_cast(unsigned short, ob);
    }
  }
  // stage xpw (Ws safe: barrier above) — batched
  {
    int4 xv[3];
#pragma unroll
    for (int i = 0; i < 3; ++i) {
      int rr = rr0 + 16 * i;
      xv[i] = make_int4(0, 0, 0, 0);
      if (rr < 40) xv[i] = *(const int4*)(xpw + ((size_t)rdir * 40 + rr) * 128 + gcol * 8);
    }
#pragma unroll
    for (int i = 0; i < 3; ++i)
      *(int4*)&Ws[(rr0 + 16 * i) * KS + gcol * 8] = xv[i];
  }
  __syncthreads();
  // ---- xproj over LDS-resident xc ----
  f32x4 acc2[3];
#pragma unroll
  for (int c = 0; c < 3; ++c) acc2[c] = zero4;
  for (int ks = 0; ks < 128; ks += 32) {
    bf16x8 af = *(const bf16x8*)&As[(wave * 16 + lm) * KS + ks + lq * 8];
#pragma unroll
    for (int c = 0; c < 3; ++c) {
      bf16x8 bfr = *(const bf16x8*)&Ws[(c * 16 + lm) * KS + ks + lq * 8];
      acc2[c] = __builtin_amdgcn_mfma_f32_16x16x32_bf16(af, bfr, acc2[c], 0, 0, 0);
    }
  }
#pragma unroll
  for (int c = 0; c < 3; ++c) {
    int col = c * 16 + lm;
#pragma unroll
    for (int e = 0; e < 4; ++e) {
      int rl = wave * 16 + lq * 4 + e;
      int m = m0 + rl;
      float v = acc2[c][e];
      if (col < DTR) dbs[rl][col] = v;
      else if (col < DTR + 2 * DS && m < BL)
        BCb[((size_t)rdir * BL + m) * 32 + (col - DTR)] = v;
    }
  }
  __syncthreads();
  {
    int dloc = tid & 127;
    int rpar = tid >> 7;
    const float* dw = dt_w_l + ((size_t)rdir * 128 + dloc) * 8;
    float dwr[8];
#pragma unroll
    for (int j = 0; j < 8; ++j) dwr[j] = dw[j];
    float db = dt_b_l[rdir * 128 + dloc];
    for (int rr = rpar; rr < 64; rr += 2) {
      int m = m0 + rr;
      if (m >= BL) break;
      float a = db;
#pragma unroll
      for (int j = 0; j < 8; ++j) a = fmaf(dbs[rr][j], dwr[j], a);
      // softplus: fast __logf (result rounded to bf16; a>20 clamp guards overflow)
      float dtv = (a > 20.f) ? a : __logf(1.f + __expf(a));
      DTbf[((size_t)rdir * BL + m) * 128 + dloc] = (__bf16)dtv;
    }
  }
}

// ---------------- scan phase A: LDS-staged inputs (bf16 DT) ----------------
// HC written TRANSPOSED: HC[(blk*DS + n)*D + d]. Direct coalesced stores (r11).
__global__ __launch_bounds__(128) void k_scanA(
    const __bf16* __restrict__ DTbf, const __bf16* __restrict__ XCCbf,
    const float* __restrict__ BCb, const float* __restrict__ Alog_l,
    float* __restrict__ HC, float* __restrict__ DTS)
{
  __shared__ float Bs[CT][DS];     // 2 KB
  __shared__ __bf16 DTs[CT][128];  // 8 KB
  __shared__ __bf16 XCs[CT][128];  // 8 KB
  int blk = blockIdx.x;
  int c  = blk % NC;
  int rb = blk / NC;
  int rdir = rb / B;
  int d = threadIdx.x;
  int s0 = c * CT;
  int cn = min(CT, L - s0);
  size_t rowbase = (size_t)rb * L + s0;

  // batched staging loads
  int totB = cn * DS;
  float bb[4]; bool bp[4];
#pragma unroll
  for (int i = 0; i < 4; ++i) {
    int q = d + i * 128;
    bp[i] = q < totB;
    bb[i] = bp[i] ? BCb[(rowbase + (q >> 4)) * 32 + (q & 15)] : 0.f;
  }
  int totD = cn * 16;
  int4 dv[4], xv[4]; bool dp[4];
#pragma unroll
  for (int i = 0; i < 4; ++i) {
    int q = d + i * 128;
    dp[i] = q < totD;
    dv[i] = make_int4(0, 0, 0, 0);
    xv[i] = make_int4(0, 0, 0, 0);
    int row = q >> 4, c8 = (q & 15) * 8;
    if (dp[i]) {
      dv[i] = *(const int4*)(DTbf + (rowbase + row) * D + c8);
      xv[i] = *(const int4*)(XCCbf + (rowbase + row) * D + c8);
    }
  }
  float An[DS];
  const float* Ab = Alog_l + (size_t)rdir * D * DS + (size_t)d * DS;
#pragma unroll
  for (int n = 0; n < DS; ++n) An[n] = -__expf(Ab[n]);
  bool fast = an_is_linear(An);
  // LDS writes after all loads issued
#pragma unroll
  for (int i = 0; i < 4; ++i) {
    int q = d + i * 128;
    if (bp[i]) Bs[q >> 4][q & 15] = bb[i];
  }
#pragma unroll
  for (int i = 0; i < 4; ++i) {
    int q = d + i * 128;
    int row = q >> 4, c8 = (q & 15) * 8;
    if (dp[i]) {
      *(int4*)&DTs[row][c8] = dv[i];
      *(int4*)&XCs[row][c8] = xv[i];
    }
  }
  __syncthreads();
  float h[DS];
#pragma unroll
  for (int n = 0; n < DS; ++n) h[n] = 0.f;
  float dts = 0.f;
  if (fast) {
    for (int ss = 0; ss < cn; ++ss) {
      float dt = (float)DTs[ss][d];
      float xc = (float)XCs[ss][d];
      dts += dt;
      float e = dt * xc;
      float pw[DS];
      pow_tree(__expf(-dt), pw);
#pragma unroll
      for (int n = 0; n < DS; ++n)
        h[n] = fmaf(pw[n], h[n], e * Bs[ss][n]);
    }
  } else {
    for (int ss = 0; ss < cn; ++ss) {
      float dt = (float)DTs[ss][d];
      float xc = (float)XCs[ss][d];
      dts += dt;
      float e = dt * xc;
#pragma unroll
      for (int n = 0; n < DS; ++n)
        h[n] = __expf(dt * An[n]) * h[n] + e * Bs[ss][n];
    }
  }
  DTS[(size_t)blk * D + d] = dts;
  // direct coalesced [n][d] stores (fixed n: 128 consecutive floats across threads)
#pragma unroll
  for (int n = 0; n < DS; ++n)
    HC[((size_t)blk * DS + n) * D + d] = h[n];
}

// ---------------- scan phase B: boundary chain, n-parallel ----------------
__global__ __launch_bounds__(128) void k_scanB(
    const float* __restrict__ HC, const float* __restrict__ DTS,
    const float* __restrict__ Alog_l, float* __restrict__ HIN)
{
  int rb = blockIdx.x >> 4;
  int n  = blockIdx.x & 15;
  int rdir = rb / B;
  int d = threadIdx.x;
  float An_v = -__expf(Alog_l[((size_t)rdir * D + d) * DS + n]);
  float hc[8], dts[8];
#pragma unroll
  for (int k = 0; k < 8; ++k) {
    int cc = (k < NC) ? k : NC - 1;
    hc[k]  = HC[((size_t)(rb * NC + cc) * DS + n) * D + d];
    dts[k] = DTS[((size_t)(rb * NC + cc)) * D + d];
  }
  float h = 0.f;
  for (int c = 0; c < NC; c += 8) {
#pragma unroll
    for (int k = 0; k < 8; ++k) {
      int cc = c + k;
      if (cc >= NC) break;
      HIN[((size_t)(rb * NC + cc) * DS + n) * D + d] = h;
      h = __expf(dts[k] * An_v) * h + hc[k];
      int cp = cc + 8 < NC ? cc + 8 : NC - 1;
      hc[k]  = HC[((size_t)(rb * NC + cp) * DS + n) * D + d];
      dts[k] = DTS[((size_t)(rb * NC + cp)) * D + d];
    }
  }
}

// ---------------- scan phase C: LDS-staged inputs, emit y bf16 ----------------
// Staging batched; HIN/A/Dp register loads hoisted before LDS writes.
__global__ __launch_bounds__(128) void k_scanC(
    const __bf16* __restrict__ DTbf, const __bf16* __restrict__ XCCbf,
    const float* __restrict__ BCb, const __bf16* __restrict__ Zbf,
    const float* __restrict__ HIN, const float* __restrict__ Alog_l,
    const float* __restrict__ Dp_l, __bf16* __restrict__ YMbf)
{
  __shared__ float Bsm[CT][DS];
  __shared__ float Csm[CT][DS];
  __shared__ __bf16 DTs[CT][128];
  __shared__ __bf16 XCs[CT][128];
  __shared__ __bf16 Zs[CT][128];
  int blk = blockIdx.x;
  int c  = blk % NC;
  int rb = blk / NC;
  int rdir = rb / B;
  int b = rb % B;
  int d = threadIdx.x;
  int s0 = c * CT;
  int cn = min(CT, L - s0);
  size_t rowbase = (size_t)rb * L + s0;

  // batched staging loads
  int tot2 = cn * 2 * DS;
  float cbv[8]; bool cbp[8];
#pragma unroll
  for (int i = 0; i < 8; ++i) {
    int q = d + i * 128;
    cbp[i] = q < tot2;
    cbv[i] = cbp[i] ? BCb[(rowbase + (q >> 5)) * 32 + (q & 31)] : 0.f;
  }
  int totD = cn * 16;
  int4 dv[4], xv[4], zv[4]; bool dp[4];
#pragma unroll
  for (int i = 0; i < 4; ++i) {
    int q = d + i * 128;
    dp[i] = q < totD;
    dv[i] = make_int4(0, 0, 0, 0);
    xv[i] = make_int4(0, 0, 0, 0);
    zv[i] = make_int4(0, 0, 0, 0);
    int row = q >> 4, c8 = (q & 15) * 8;
    if (dp[i]) {
      dv[i] = *(const int4*)(DTbf + (rowbase + row) * D + c8);
      xv[i] = *(const int4*)(XCCbf + (rowbase + row) * D + c8);
      zv[i] = *(const int4*)(Zbf + (rowbase + row) * D + c8);
    }
  }
  float An[DS];
  const float* Ab = Alog_l + (size_t)rdir * D * DS + (size_t)d * DS;
#pragma unroll
  for (int n = 0; n < DS; ++n) An[n] = -__expf(Ab[n]);
  bool fast = an_is_linear(An);
  float h[DS];
#pragma unroll
  for (int n = 0; n < DS; ++n)
    h[n] = HIN[((size_t)blk * DS + n) * D + d];   // [n][d] layout: coalesced
  float Dpv = Dp_l[rdir * D + d];
  // LDS writes after all loads issued
#pragma unroll
  for (int i = 0; i < 8; ++i) {
    int q = d + i * 128;
    if (cbp[i]) {
      int ss = q >> 5, j = q & 31;
      if (j < DS) Bsm[ss][j] = cbv[i]; else Csm[ss][j - DS] = cbv[i];
    }
  }
#pragma unroll
  for (int i = 0; i < 4; ++i) {
    int q = d + i * 128;
    int row = q >> 4, c8 = (q & 15) * 8;
    if (dp[i]) {
      *(int4*)&DTs[row][c8] = dv[i];
      *(int4*)&XCs[row][c8] = xv[i];
      *(int4*)&Zs[row][c8]  = zv[i];
    }
  }
  __syncthreads();
  if (fast) {
    for (int ss = 0; ss < cn; ++ss) {
      float dt = (float)DTs[ss][d];
      float xc = (float)XCs[ss][d];
      float z  = (float)Zs[ss][d];
      float e = dt * xc;
      float pw[DS];
      pow_tree(__expf(-dt), pw);
      float y = xc * Dpv;
#pragma unroll
      for (int n = 0; n < DS; ++n) {
        h[n] = fmaf(pw[n], h[n], e * Bsm[ss][n]);
        y = fmaf(h[n], Csm[ss][n], y);
      }
      y *= z * sigmoidf_(z);
      int s = s0 + ss;
      int tt = rdir ? (L - 1 - s) : s;
      YMbf[((size_t)b * L + tt) * 256 + rdir * 128 + d] = (__bf16)y;
    }
  } else {
    for (int ss = 0; ss < cn; ++ss) {
      float dt = (float)DTs[ss][d];
      float xc = (float)XCs[ss][d];
      float z  = (float)Zs[ss][d];
      float e = dt * xc;
      float y = xc * Dpv;
#pragma unroll
      for (int n = 0; n < DS; ++n) {
        h[n] = __expf(dt * An[n]) * h[n] + e * Bsm[ss][n];
        y = fmaf(h[n], Csm[ss][n], y);
      }
      y *= z * sigmoidf_(z);
      int s = s0 + ss;
      int tt = rdir ? (L - 1 - s) : s;
      YMbf[((size_t)b * L + tt) * 256 + rdir * 128 + d] = (__bf16)y;
    }
  }
}

// ---------------- fused tail: outproj + LN1 + FFN1 + FFN2 + LN2 (+ final LN/out on last) ----------------
// 32-row tiles (grid 513 -> 2 blocks/CU, round-3 verified structure) grafted
// with batched stage loads + one-ahead register prefetch (round-5/6 discipline)
// and uvp U-preload. Barrier positions identical to round-3's passing kernel.
__global__ __launch_bounds__(256) void k_tail(
    const __bf16* __restrict__ YMbf, const __bf16* __restrict__ Wout,
    const float* __restrict__ g1, const float* __restrict__ be1,
    const __bf16* __restrict__ w1bf, const float* __restrict__ b1,
    const __bf16* __restrict__ w2bf, const float* __restrict__ b2,
    const float* __restrict__ g2, const float* __restrict__ be2,
    float* __restrict__ U, __bf16* __restrict__ Ubf,
    int last, const float* __restrict__ lnfg, const float* __restrict__ lnfb,
    float* __restrict__ outp)
{
  __shared__ short AX[32 * KS];      //  8704 B : YM stage -> XR bf16
  __shared__ short HB[32 * HS];      // 16896 B : H bf16 (256 cols)
  __shared__ short Ws[128 * KS];     // 34816 B : weight staging (128 rows)
  __shared__ float red[2][32][2];    //   512 B : cross-wave LN partials
  int m0 = blockIdx.x * 32;
  int tid = threadIdx.x;
  int wave = tid >> 6, lane = tid & 63, lm = lane & 15, lq = lane >> 4;
  int wm = wave >> 1, wn = wave & 1;
  int rr0 = tid >> 4, gcol = tid & 15;
  f32x4 zero4 = {0.f, 0.f, 0.f, 0.f};

  // ---- prefetch phase-1 panels (needed first) ----
  int4 ym0[2], ym1[2], wo0[8], wo1[8];
#pragma unroll
  for (int j = 0; j < 2; ++j) {
    int m = m0 + rr0 + j * 16;
    ym0[j] = make_int4(0, 0, 0, 0);
    if (m < BL) ym0[j] = *(const int4*)(YMbf + (size_t)m * 256 + gcol * 8);
  }
#pragma unroll
  for (int j = 0; j < 8; ++j)
    wo0[j] = *(const int4*)(Wout + (size_t)(rr0 + j * 16) * 256 + gcol * 8);
#pragma unroll
  for (int j = 0; j < 2; ++j) {
    int m = m0 + rr0 + j * 16;
    ym1[j] = make_int4(0, 0, 0, 0);
    if (m < BL) ym1[j] = *(const int4*)(YMbf + (size_t)m * 256 + 128 + gcol * 8);
  }
#pragma unroll
  for (int j = 0; j < 8; ++j)
    wo1[j] = *(const int4*)(Wout + (size_t)(rr0 + j * 16) * 256 + 128 + gcol * 8);

  // ---- U preload for LN1 ----
  float uvp[4][4];
#pragma unroll
  for (int r = 0; r < 4; ++r) {
    int row = m0 + wm * 16 + lq * 4 + r;
    bool valid = row < BL;
#pragma unroll
    for (int c = 0; c < 4; ++c) {
      int col = wn * 64 + c * 16 + lm;
      uvp[r][c] = valid ? U[(size_t)row * 128 + col] : 0.f;
    }
  }

  // ---- phase 1: outproj (K=256), C[32][128] ----
  int4 w1t0[8], w1t1[8];
  f32x4 acc[4];
#pragma unroll
  for (int c = 0; c < 4; ++c) acc[c] = zero4;
#pragma unroll
  for (int kc = 0; kc < 2; ++kc) {
    if (kc) __syncthreads();
#pragma unroll
    for (int j = 0; j < 2; ++j)
      *(int4*)&AX[(rr0 + j * 16) * KS + gcol * 8] = kc ? ym1[j] : ym0[j];
#pragma unroll
    for (int j = 0; j < 8; ++j)
      *(int4*)&Ws[(rr0 + j * 16) * KS + gcol * 8] = kc ? wo1[j] : wo0[j];
    if (kc == 1) {
      // issue w1 prefetch (both halves; wo regs die above)
#pragma unroll
      for (int j = 0; j < 8; ++j)
        w1t0[j] = *(const int4*)(w1bf + (size_t)(0 * 128 + rr0 + j * 16) * 128 + gcol * 8);
#pragma unroll
      for (int j = 0; j < 8; ++j)
        w1t1[j] = *(const int4*)(w1bf + (size_t)(1 * 128 + rr0 + j * 16) * 128 + gcol * 8);
    }
    __syncthreads();
    for (int ks = 0; ks < 128; ks += 32) {
      bf16x8 af = *(const bf16x8*)&AX[(wm * 16 + lm) * KS + ks + lq * 8];
#pragma unroll
      for (int c = 0; c < 4; ++c) {
        bf16x8 bfr = *(const bf16x8*)&Ws[(wn * 64 + c * 16 + lm) * KS + ks + lq * 8];
        acc[c] = __builtin_amdgcn_mfma_f32_16x16x32_bf16(af, bfr, acc[c], 0, 0, 0);
      }
    }
  }
  __syncthreads();   // all MFMA reads of AX/Ws done

  // ---- phase 2: residual + LN1 -> XR bf16 in AX (cross-wave via red) ----
  {
    float g1c[4], be1c[4];
#pragma unroll
    for (int c = 0; c < 4; ++c) {
      int col = wn * 64 + c * 16 + lm;
      g1c[c] = g1[col]; be1c[c] = be1[col];
    }
    float os[4][4];
    float mean[4];
#pragma unroll
    for (int r = 0; r < 4; ++r) {
      int rl = wm * 16 + lq * 4 + r;
      float s = 0.f;
#pragma unroll
      for (int c = 0; c < 4; ++c) {
        os[r][c] = acc[c][r] + uvp[r][c];
        s += os[r][c];
      }
#pragma unroll
      for (int mm = 1; mm < 16; mm <<= 1) s += __shfl_xor(s, mm, 64);
      if (lm == 0) red[0][rl][wn] = s;
    }
    __syncthreads();
#pragma unroll
    for (int r = 0; r < 4; ++r) {
      int rl = wm * 16 + lq * 4 + r;
      mean[r] = (red[0][rl][0] + red[0][rl][1]) * (1.f / 128.f);
      float qv = 0.f;
#pragma unroll
      for (int c = 0; c < 4; ++c) { float dv = os[r][c] - mean[r]; qv += dv * dv; }
#pragma unroll
      for (int mm = 1; mm < 16; mm <<= 1) qv += __shfl_xor(qv, mm, 64);
      if (lm == 0) red[1][rl][wn] = qv;
    }
    __syncthreads();
#pragma unroll
    for (int r = 0; r < 4; ++r) {
      int rl = wm * 16 + lq * 4 + r;
      float inv = rsqrtf((red[1][rl][0] + red[1][rl][1]) * (1.f / 128.f) + 1e-5f);
#pragma unroll
      for (int c = 0; c < 4; ++c) {
        int col = wn * 64 + c * 16 + lm;
        float o = (os[r][c] - mean[r]) * inv * g1c[c] + be1c[c];
        AX[rl * KS + col] = (short)__builtin_bit_cast(unsigned short, (__bf16)o);
      }
    }
  }
  // (FFN1's post-stage barrier orders AX writes vs reads)

  // ---- phase 3: FFN1 (K=128), 2 rounds of 128 N-rows, H -> HB ----
  int4 w2k0[8], w2k1[8];
#pragma unroll
  for (int t = 0; t < 2; ++t) {
    if (t) __syncthreads();
#pragma unroll
    for (int j = 0; j < 8; ++j)
      *(int4*)&Ws[(rr0 + j * 16) * KS + gcol * 8] = t ? w1t1[j] : w1t0[j];
    if (t == 1) {
      // issue w2 prefetch (w1 regs die above)
#pragma unroll
      for (int j = 0; j < 8; ++j)
        w2k0[j] = *(const int4*)(w2bf + (size_t)(rr0 + j * 16) * 256 + gcol * 8);
#pragma unroll
      for (int j = 0; j < 8; ++j)
        w2k1[j] = *(const int4*)(w2bf + (size_t)(rr0 + j * 16) * 256 + 128 + gcol * 8);
    }
    __syncthreads();
    f32x4 a1[4];
#pragma unroll
    for (int c = 0; c < 4; ++c) a1[c] = zero4;
    for (int ks = 0; ks < 128; ks += 32) {
      bf16x8 af = *(const bf16x8*)&AX[(wm * 16 + lm) * KS + ks + lq * 8];
#pragma unroll
      for (int c = 0; c < 4; ++c) {
        bf16x8 bfr = *(const bf16x8*)&Ws[(wn * 64 + c * 16 + lm) * KS + ks + lq * 8];
        a1[c] = __builtin_amdgcn_mfma_f32_16x16x32_bf16(af, bfr, a1[c], 0, 0, 0);
      }
    }
#pragma unroll
    for (int c = 0; c < 4; ++c) {
      int col = t * 128 + wn * 64 + c * 16 + lm;
      float bb = b1[col];
#pragma unroll
      for (int e = 0; e < 4; ++e) {
        int rl = wm * 16 + lq * 4 + e;
        float hv = fmaxf(a1[c][e] + bb, 0.f);
        HB[rl * HS + col] = (short)__builtin_bit_cast(unsigned short, (__bf16)hv);
      }
    }
  }

  // ---- phase 4: FFN2 (K=256), accumulate over kc ----
  f32x4 a2[4];
#pragma unroll
  for (int c = 0; c < 4; ++c) a2[c] = zero4;
#pragma unroll
  for (int kc = 0; kc < 2; ++kc) {
    __syncthreads();   // Ws reads done + (kc==0) HB writes drained
#pragma unroll
    for (int j = 0; j < 8; ++j)
      *(int4*)&Ws[(rr0 + j * 16) * KS + gcol * 8] = kc ? w2k1[j] : w2k0[j];
    __syncthreads();
    for (int ks = 0; ks < 128; ks += 32) {
      bf16x8 af = *(const bf16x8*)&HB[(wm * 16 + lm) * HS + kc * 128 + ks + lq * 8];
#pragma unroll
      for (int c = 0; c < 4; ++c) {
        bf16x8 bfr = *(const bf16x8*)&Ws[(wn * 64 + c * 16 + lm) * KS + ks + lq * 8];
        a2[c] = __builtin_amdgcn_mfma_f32_16x16x32_bf16(af, bfr, a2[c], 0, 0, 0);
      }
    }
  }
  __syncthreads();   // orders a2 vs AX rewrite below

  // ---- phase 5: FFN2 bias + residual + LN2 (+ lnf/out on last) ----
  {
    float b2c[4], g2c[4], be2c[4];
#pragma unroll
    for (int c = 0; c < 4; ++c) {
      int col = wn * 64 + c * 16 + lm;
      b2c[c] = b2[col]; g2c[c] = g2[col]; be2c[c] = be2[col];
    }
    float os[4][4];
    float mean[4];
#pragma unroll
    for (int r = 0; r < 4; ++r) {
      int rl = wm * 16 + lq * 4 + r;
      float s = 0.f;
#pragma unroll
      for (int c = 0; c < 4; ++c) {
        int col = wn * 64 + c * 16 + lm;
        __bf16 xb = __builtin_bit_cast(__bf16, (unsigned short)AX[rl * KS + col]);
        os[r][c] = a2[c][r] + b2c[c] + (float)xb;
        s += os[r][c];
      }
#pragma unroll
      for (int mm = 1; mm < 16; mm <<= 1) s += __shfl_xor(s, mm, 64);
      if (lm == 0) red[0][rl][wn] = s;
    }
    __syncthreads();
#pragma unroll
    for (int r = 0; r < 4; ++r) {
      int rl = wm * 16 + lq * 4 + r;
      mean[r] = (red[0][rl][0] + red[0][rl][1]) * (1.f / 128.f);
      float qv = 0.f;
#pragma unroll
      for (int c = 0; c < 4; ++c) { float dv = os[r][c] - mean[r]; qv += dv * dv; }
#pragma unroll
      for (int mm = 1; mm < 16; mm <<= 1) qv += __shfl_xor(qv, mm, 64);
      if (lm == 0) red[1][rl][wn] = qv;
    }
    __syncthreads();
    float o[4][4];
#pragma unroll
    for (int r = 0; r < 4; ++r) {
      int rl = wm * 16 + lq * 4 + r;
      float inv = rsqrtf((red[1][rl][0] + red[1][rl][1]) * (1.f / 128.f) + 1e-5f);
#pragma unroll
      for (int c = 0; c < 4; ++c)
        o[r][c] = (os[r][c] - mean[r]) * inv * g2c[c] + be2c[c];
    }
    if (!last) {
#pragma unroll
      for (int r = 0; r < 4; ++r) {
        int rl = wm * 16 + lq * 4 + r;
        int row = m0 + rl;
        if (row < BL) {
#pragma unroll
          for (int c = 0; c < 4; ++c) {
            int col = wn * 64 + c * 16 + lm;
            U[(size_t)row * 128 + col] = o[r][c];
          }
        }
#pragma unroll
        for (int c = 0; c < 4; ++c) {
          int col = wn * 64 + c * 16 + lm;
          AX[rl * KS + col] = (short)__builtin_bit_cast(unsigned short, (__bf16)o[r][c]);
        }
      }
    } else {
      // final LN (lnf) + transposed out store
      float m2[4];
#pragma unroll
      for (int r = 0; r < 4; ++r) {
        int rl = wm * 16 + lq * 4 + r;
        float s2 = 0.f;
#pragma unroll
        for (int c = 0; c < 4; ++c) s2 += o[r][c];
#pragma unroll
        for (int mm = 1; mm < 16; mm <<= 1) s2 += __shfl_xor(s2, mm, 64);
        if (lm == 0) red[0][rl][wn] = s2;
      }
      __syncthreads();
#pragma unroll
      for (int r = 0; r < 4; ++r) {
        int rl = wm * 16 + lq * 4 + r;
        m2[r] = (red[0][rl][0] + red[0][rl][1]) * (1.f / 128.f);
        float q2 = 0.f;
#pragma unroll
        for (int c = 0; c < 4; ++c) { float dv = o[r][c] - m2[r]; q2 += dv * dv; }
#pragma unroll
        for (int mm = 1; mm < 16; mm <<= 1) q2 += __shfl_xor(q2, mm, 64);
        if (lm == 0) red[1][rl][wn] = q2;
      }
      __syncthreads();
#pragma unroll
      for (int r = 0; r < 4; ++r) {
        int rl = wm * 16 + lq * 4 + r;
        int row = m0 + rl;
        float i2 = rsqrtf((red[1][rl][0] + red[1][rl][1]) * (1.f / 128.f) + 1e-5f);
        if (row < BL) {
          int bb = row / L;
          int t = row - bb * L;
          if (t < N * P) {
            int n = t >> 7, p = t & 127;
            size_t obase = (((size_t)bb * N + n) * D) * P + p;
#pragma unroll
            for (int c = 0; c < 4; ++c) {
              int col = wn * 64 + c * 16 + lm;
              float o2 = (o[r][c] - m2[r]) * i2 * lnfg[col] + lnfb[col];
              outp[obase + (size_t)col * P] = o2;
            }
          }
        }
      }
    }
  }
  if (!last) {
    __syncthreads();
    // coalesced Ubf store from AX (32 rows x 16 groups = 512 int4)
#pragma unroll
    for (int i = 0; i < 2; ++i) {
      int rr = rr0 + 16 * i;
      int m = m0 + rr;
      if (m < BL)
        *(int4*)(Ubf + (size_t)m * 128 + gcol * 8) = *(const int4*)&AX[rr * KS + gcol * 8];
    }
  }
}

extern "C" void kernel_launch(void* const* d_in, const int* in_sizes, int n_in,
                              void* d_out, int out_size, void* d_ws, size_t ws_size,
                              hipStream_t stream)
{
  (void)in_sizes; (void)n_in; (void)out_size; (void)ws_size;
  const float* x       = (const float*)d_in[0];
  const float* view    = (const float*)d_in[1];
  const float* wp_w    = (const float*)d_in[2];
  const float* wp_b    = (const float*)d_in[3];
  const float* m_in_w  = (const float*)d_in[4];
  const float* m_conv_w= (const float*)d_in[5];
  const float* m_conv_b= (const float*)d_in[6];
  const float* m_xproj = (const float*)d_in[7];
  const float* m_dt_w  = (const float*)d_in[8];
  const float* m_dt_b  = (const float*)d_in[9];
  const float* m_Alog  = (const float*)d_in[10];
  const float* m_Dp    = (const float*)d_in[11];
  const float* m_out_w = (const float*)d_in[12];
  const float* ffn_w1  = (const float*)d_in[13];
  const float* ffn_b1  = (const float*)d_in[14];
  const float* ffn_w2  = (const float*)d_in[15];
  const float* ffn_b2  = (const float*)d_in[16];
  const float* ln1_g   = (const float*)d_in[17];
  const float* ln1_b   = (const float*)d_in[18];
  const float* ln2_g   = (const float*)d_in[19];
  const float* ln2_b   = (const float*)d_in[20];
  const float* lnf_g   = (const float*)d_in[21];
  const float* lnf_b   = (const float*)d_in[22];
  float* out = (float*)d_out;

  float* W = (float*)d_ws;
  size_t off = 0;
  auto alloc = [&](size_t nfl) { float* p = W + off; off += (nfl + 3) & ~(size_t)3; return p; };
  float* U      = alloc((size_t)BL * D);
  float* Ubf_f  = alloc((size_t)BL * D / 2);
  float* XCC_f  = alloc((size_t)BL * D);          // 2*BL*D bf16
  float* Zbf_f  = alloc((size_t)BL * D);          // 2*BL*D bf16
  float* DT_f   = alloc((size_t)BL * D);          // 2*BL*D bf16
  float* BCb    = alloc((size_t)2 * BL * 2 * DS);
  float* YM_f   = alloc((size_t)BL * 256 / 2);
  float* HC     = alloc((size_t)2 * B * NC * D * DS);
  float* DTS    = alloc((size_t)2 * B * NC * D);
  float* HIN    = alloc((size_t)2 * B * NC * D * DS);
  float* weff_f = alloc(262144 / 2);
  float* xpw_f  = alloc(20480 / 2);
  float* outw_f = alloc(65536 / 2);
  float* w1_f   = alloc(65536 / 2);
  float* w2_f   = alloc(65536 / 2);

  __bf16* Ubf    = (__bf16*)Ubf_f;
  __bf16* XCCbf  = (__bf16*)XCC_f;
  __bf16* Zbf    = (__bf16*)Zbf_f;
  __bf16* DTbf   = (__bf16*)DT_f;
  __bf16* YMbf   = (__bf16*)YM_f;
  __bf16* weff   = (__bf16*)weff_f;
  __bf16* xpw_bf = (__bf16*)xpw_f;
  __bf16* outw_bf= (__bf16*)outw_f;
  __bf16* w1_bf  = (__bf16*)w1_f;
  __bf16* w2_bf  = (__bf16*)w2_f;

  k_init<<<PREP_BLOCKS + EMBED_BLOCKS, 256, 0, stream>>>(
      m_in_w, m_conv_w, m_xproj, m_out_w, ffn_w1, ffn_w2,
      weff, xpw_bf, outw_bf, w1_bf, w2_bf,
      x, view, wp_w, wp_b, U, Ubf);

  for (int l = 0; l < EL; ++l) {
    const float* conv_b_l = m_conv_b + (size_t)l * 2 * D;
    const float* dt_w_l   = m_dt_w   + (size_t)l * 2 * D * DTR;
    const float* dt_b_l   = m_dt_b   + (size_t)l * 2 * D;
    const float* Alog_l   = m_Alog   + (size_t)l * 2 * D * DS;
    const float* Dp_l     = m_Dp     + (size_t)l * 2 * D;

    k_front <<<dim3(2 * MT64, 2), 256, 0, stream>>>(
        Ubf, weff + (size_t)l * 2 * 256 * 256, conv_b_l,
        xpw_bf + (size_t)l * 2 * 40 * 128, dt_w_l, dt_b_l,
        XCCbf, Zbf, BCb, DTbf);
    k_scanA <<<2 * B * NC, 128, 0, stream>>>(DTbf, XCCbf, BCb, Alog_l, HC, DTS);
    k_scanB <<<2 * B * 16, 128, 0, stream>>>(HC, DTS, Alog_l, HIN);
    k_scanC <<<2 * B * NC, 128, 0, stream>>>(DTbf, XCCbf, BCb, Zbf, HIN, Alog_l, Dp_l, YMbf);
    k_tail  <<<MT32, 256, 0, stream>>>(
        YMbf, outw_bf + (size_t)l * 128 * 256,
        ln1_g + l * D, ln1_b + l * D,
        w1_bf + (size_t)l * 256 * 128, ffn_b1 + l * DFF,
        w2_bf + (size_t)l * 128 * 256, ffn_b2 + l * D,
        ln2_g + l * D, ln2_b + l * D, U, Ubf,
        (l == EL - 1) ? 1 : 0, lnf_g, lnf_b, out);
  }
}

// Round 15
// 280.044 us; speedup vs baseline: 1.2461x; 1.2461x over previous
//
#include <hip/hip_runtime.h>
#include <hip/hip_bf16.h>
#include <math.h>

#define DEV __device__ __forceinline__

constexpr int B  = 8,  N = 16, P = 128, PL = 16;
constexpr int D  = 128, DS = 16, DTR = 8, DFF = 256, EL = 2;
constexpr int L  = N * P + 1;            // 2049
constexpr int BL = B * L;                // 16392
constexpr int CT = 32;                   // scan chunk length (32: verified best)
constexpr int NC = (L + CT - 1) / CT;    // 65
constexpr int MT64  = (BL + 63) / 64;    // 257
constexpr int KS = 136;                  // LDS row stride (bf16/short units)
constexpr int HS = 264;                  // LDS row stride for H (256+8)
constexpr int PREP_BLOCKS  = 1872;
constexpr int EMBED_BLOCKS = (BL * D + 255) / 256;  // 8196

using bf16x8 = __attribute__((ext_vector_type(8))) __bf16;
using f32x4  = __attribute__((ext_vector_type(4))) float;

DEV float sigmoidf_(float x) { return 1.0f / (1.0f + __expf(-x)); }

// r^(n+1) for n=0..15, depth-4 tree
DEV void pow_tree(float r, float* pw) {
  float r2 = r * r;
  float r3 = r2 * r;
  float r4 = r2 * r2;
  float r8 = r4 * r4;
  float r12 = r8 * r4;
  pw[0] = r;       pw[1] = r2;      pw[2] = r3;      pw[3] = r4;
  pw[4] = r4 * r;  pw[5] = r4 * r2; pw[6] = r4 * r3; pw[7] = r8;
  pw[8] = r8 * r;  pw[9] = r8 * r2; pw[10] = r8 * r3; pw[11] = r12;
  pw[12] = r12 * r; pw[13] = r12 * r2; pw[14] = r12 * r3; pw[15] = r12 * r4;
}

// A_n check: A_init = log(1..16) broadcast -> A_n = -(n+1) exactly.
DEV bool an_is_linear(const float* An) {
  bool ok = true;
#pragma unroll
  for (int n = 0; n < DS; ++n)
    ok = ok && (fabsf(An[n] + (float)(n + 1)) < 1e-3f * (n + 1));
  return ok;
}

// ---------------- merged init: weight prep (blocks 0..1871) + patch embed ----------------
__global__ __launch_bounds__(256) void k_init(
    const float* __restrict__ in_w, const float* __restrict__ conv_w,
    const float* __restrict__ xproj, const float* __restrict__ out_w,
    const float* __restrict__ w1, const float* __restrict__ w2,
    __bf16* __restrict__ weff, __bf16* __restrict__ xpw_bf,
    __bf16* __restrict__ outw_bf, __bf16* __restrict__ w1_bf,
    __bf16* __restrict__ w2_bf,
    const float* __restrict__ x, const float* __restrict__ view,
    const float* __restrict__ wp_w, const float* __restrict__ wp_b,
    float* __restrict__ U, __bf16* __restrict__ Ubf)
{
  int bid = blockIdx.x;
  if (bid < PREP_BLOCKS) {
    int g = bid * 256 + threadIdx.x;
    if (g < 262144) {
      int l = g >> 17;
      int r = g & 131071;
      int dir = r >> 16;
      int r2 = r & 65535;
      int col = r2 >> 8;
      int kk = r2 & 255;
      int chunk = kk >> 7, k = kk & 127;
      int ld = l * 2 + dir;
      float v;
      if (col < 128) {
        v = in_w[((size_t)ld * 256 + col) * 128 + k] *
            conv_w[((size_t)ld * 128 + col) * 2 + chunk];
      } else {
        v = chunk ? in_w[((size_t)ld * 256 + col) * 128 + k] : 0.f;
      }
      weff[((size_t)ld * 256 + col) * 256 + chunk * 128 + k] = (__bf16)v;
      return;
    }
    g -= 262144;
    if (g < 20480) { xpw_bf[g] = (__bf16)xproj[g]; return; }
    g -= 20480;
    if (g < 65536) {
      int k = g & 127; int q = g >> 7; int n = q & 127; int q2 = q >> 7;
      int dir = q2 & 1; int l = q2 >> 1;
      outw_bf[((size_t)(l * 128 + n)) * 256 + dir * 128 + k] = (__bf16)out_w[g];
      return;
    }
    g -= 65536;
    if (g < 65536) { w1_bf[g] = (__bf16)w1[g]; return; }
    g -= 65536;
    if (g < 65536) { w2_bf[g] = (__bf16)w2[g]; return; }
    return;
  }
  // embed part
  int g = (bid - PREP_BLOCKS) * 256 + threadIdx.x;
  if (g >= BL * D) return;
  int d = g & (D - 1);
  int row = g >> 7;
  int b = row / L, t = row % L;
  float acc;
  if (t < N * P) {
    const float* xr = x + ((size_t)b * N * P + t) * PL;
    acc = wp_b[d];
#pragma unroll
    for (int k = 0; k < PL; ++k) acc += xr[k] * wp_w[d * PL + k];
  } else {
    acc = view[b * D + d];
  }
  U[(size_t)row * D + d] = acc;
  Ubf[(size_t)row * D + d] = (__bf16)acc;
}

// ---------------- fused front: xz GEMM + conv + silu + xproj + dt ----------------
// Staging loops batched (round-5). dt softplus uses fast __logf (round-10).
// W panels register-prefetched at kernel start (round-11).
__global__ __launch_bounds__(256) void k_front(
    const __bf16* __restrict__ Ubf, const __bf16* __restrict__ Weff,
    const float* __restrict__ conv_b_l, const __bf16* __restrict__ xpw,
    const float* __restrict__ dt_w_l, const float* __restrict__ dt_b_l,
    __bf16* __restrict__ XCCbf, __bf16* __restrict__ Zbf,
    float* __restrict__ BCb, __bf16* __restrict__ DTbf)
{
  __shared__ short As[64 * KS];    // 17408 B : U staging -> later xc bf16
  __shared__ short Ws[64 * KS];    // 17408 B : weight staging
  __shared__ float dbs[64][9];     //  2304 B
  int bx = blockIdx.x;
  int rdir = bx / MT64;
  int tile = bx % MT64;
  bool isx = (blockIdx.y == 0);
  int tid = threadIdx.x;
  int m0 = tile * 64;
  const __bf16* Wb = Weff + (size_t)rdir * 256 * 256;
  int wave = tid >> 6, lane = tid & 63, lm = lane & 15, lq = lane >> 4;
  int rr0 = tid >> 4, gcol = tid & 15;
  int kc0 = isx ? 0 : 1;
  int colx = isx ? 0 : 128;

  // ---- prefetch W panels into regs (phase pidx = (kc-kc0)*2+ch) ----
  int4 wpA[4], wpB[4], wpC[4], wpD[4];
#pragma unroll
  for (int j = 0; j < 4; ++j)
    wpA[j] = *(const int4*)(Wb + (size_t)(colx + 0 * 64 + rr0 + 16 * j) * 256 + kc0 * 128 + gcol * 8);
#pragma unroll
  for (int j = 0; j < 4; ++j)
    wpB[j] = *(const int4*)(Wb + (size_t)(colx + 1 * 64 + rr0 + 16 * j) * 256 + kc0 * 128 + gcol * 8);
  if (isx) {
#pragma unroll
    for (int j = 0; j < 4; ++j)
      wpC[j] = *(const int4*)(Wb + (size_t)(colx + 0 * 64 + rr0 + 16 * j) * 256 + 128 + gcol * 8);
#pragma unroll
    for (int j = 0; j < 4; ++j)
      wpD[j] = *(const int4*)(Wb + (size_t)(colx + 1 * 64 + rr0 + 16 * j) * 256 + 128 + gcol * 8);
  }

  // per-thread A-row precompute (4 rows, one 16B column-group each)
  int aoff[4];
  unsigned vmask = 0, smask = 0;
  int shif = rdir ? 128 : -128;     // element delta for kc=0 (shifted row)
#pragma unroll
  for (int i = 0; i < 4; ++i) {
    int rr = rr0 + 16 * i;
    int m = m0 + rr;
    aoff[i] = 0;
    if (m < BL) {
      int b = m / L, s = m - b * L;
      int idx1 = rdir ? (L - 1 - s) : s;
      aoff[i] = (b * L + idx1) * 128 + gcol * 8;
      vmask |= 1u << i;
      if (s >= 1) smask |= 1u << i;
    }
  }

  f32x4 zero4 = {0.f, 0.f, 0.f, 0.f};
  f32x4 acc[8];
#pragma unroll
  for (int c = 0; c < 8; ++c) acc[c] = zero4;

  for (int kc = kc0; kc < 2; ++kc) {
    if (kc != kc0) __syncthreads();
    // stage A (64 rows): batch loads -> writes
    {
      int4 av[4];
#pragma unroll
      for (int i = 0; i < 4; ++i) {
        av[i] = make_int4(0, 0, 0, 0);
        bool ok = (vmask >> i) & 1;
        if (kc == 0) ok = ok && ((smask >> i) & 1);
        if (ok) av[i] = *(const int4*)(Ubf + aoff[i] + (kc == 0 ? shif : 0));
      }
#pragma unroll
      for (int i = 0; i < 4; ++i)
        *(int4*)&As[(rr0 + 16 * i) * KS + gcol * 8] = av[i];
    }
    for (int ch = 0; ch < 2; ++ch) {
      if (ch) __syncthreads();
      {
        int pidx = (kc - kc0) * 2 + ch;
#pragma unroll
        for (int i = 0; i < 4; ++i) {
          int4 wv = (pidx == 0) ? wpA[i] : (pidx == 1) ? wpB[i] : (pidx == 2) ? wpC[i] : wpD[i];
          *(int4*)&Ws[(rr0 + 16 * i) * KS + gcol * 8] = wv;
        }
      }
      __syncthreads();
      for (int ks = 0; ks < 128; ks += 32) {
        bf16x8 af = *(const bf16x8*)&As[(wave * 16 + lm) * KS + ks + lq * 8];
#pragma unroll
        for (int c = 0; c < 4; ++c) {
          bf16x8 bfr = *(const bf16x8*)&Ws[(c * 16 + lm) * KS + ks + lq * 8];
          acc[ch * 4 + c] = __builtin_amdgcn_mfma_f32_16x16x32_bf16(af, bfr, acc[ch * 4 + c], 0, 0, 0);
        }
      }
    }
  }

  if (!isx) {
    // z epilogue: direct scatter stores
#pragma unroll
    for (int cg = 0; cg < 8; ++cg) {
      int col = cg * 16 + lm;
#pragma unroll
      for (int e = 0; e < 4; ++e) {
        int m = m0 + wave * 16 + lq * 4 + e;
        if (m < BL)
          Zbf[((size_t)rdir * BL + m) * 128 + col] = (__bf16)acc[cg][e];
      }
    }
    return;
  }

  // x epilogue: conv bias + silu -> scatter XCC store + xc bf16 into As (wave-private rows)
  __syncthreads();   // all MFMA reads of As/Ws done
#pragma unroll
  for (int cg = 0; cg < 8; ++cg) {
    int col = cg * 16 + lm;
    float cb = conv_b_l[rdir * 128 + col];
#pragma unroll
    for (int e = 0; e < 4; ++e) {
      int rl = wave * 16 + lq * 4 + e;
      int m = m0 + rl;
      float v = acc[cg][e] + cb;
      float o = v * sigmoidf_(v);
      __bf16 ob = (__bf16)o;
      if (m < BL) XCCbf[((size_t)rdir * BL + m) * 128 + col] = ob;
      As[rl * KS + col] = (short)__builtin_bit_cast(unsigned short, ob);
    }
  }
  // stage xpw (Ws safe: barrier above) — batched
  {
    int4 xv[3];
#pragma unroll
    for (int i = 0; i < 3; ++i) {
      int rr = rr0 + 16 * i;
      xv[i] = make_int4(0, 0, 0, 0);
      if (rr < 40) xv[i] = *(const int4*)(xpw + ((size_t)rdir * 40 + rr) * 128 + gcol * 8);
    }
#pragma unroll
    for (int i = 0; i < 3; ++i)
      *(int4*)&Ws[(rr0 + 16 * i) * KS + gcol * 8] = xv[i];
  }
  __syncthreads();
  // ---- xproj over LDS-resident xc ----
  f32x4 acc2[3];
#pragma unroll
  for (int c = 0; c < 3; ++c) acc2[c] = zero4;
  for (int ks = 0; ks < 128; ks += 32) {
    bf16x8 af = *(const bf16x8*)&As[(wave * 16 + lm) * KS + ks + lq * 8];
#pragma unroll
    for (int c = 0; c < 3; ++c) {
      bf16x8 bfr = *(const bf16x8*)&Ws[(c * 16 + lm) * KS + ks + lq * 8];
      acc2[c] = __builtin_amdgcn_mfma_f32_16x16x32_bf16(af, bfr, acc2[c], 0, 0, 0);
    }
  }
#pragma unroll
  for (int c = 0; c < 3; ++c) {
    int col = c * 16 + lm;
#pragma unroll
    for (int e = 0; e < 4; ++e) {
      int rl = wave * 16 + lq * 4 + e;
      int m = m0 + rl;
      float v = acc2[c][e];
      if (col < DTR) dbs[rl][col] = v;
      else if (col < DTR + 2 * DS && m < BL)
        BCb[((size_t)rdir * BL + m) * 32 + (col - DTR)] = v;
    }
  }
  __syncthreads();
  {
    int dloc = tid & 127;
    int rpar = tid >> 7;
    const float* dw = dt_w_l + ((size_t)rdir * 128 + dloc) * 8;
    float dwr[8];
#pragma unroll
    for (int j = 0; j < 8; ++j) dwr[j] = dw[j];
    float db = dt_b_l[rdir * 128 + dloc];
    for (int rr = rpar; rr < 64; rr += 2) {
      int m = m0 + rr;
      if (m >= BL) break;
      float a = db;
#pragma unroll
      for (int j = 0; j < 8; ++j) a = fmaf(dbs[rr][j], dwr[j], a);
      // softplus: fast __logf (result rounded to bf16; a>20 clamp guards overflow)
      float dtv = (a > 20.f) ? a : __logf(1.f + __expf(a));
      DTbf[((size_t)rdir * BL + m) * 128 + dloc] = (__bf16)dtv;
    }
  }
}

// ---------------- scan phase A: LDS-staged inputs (bf16 DT) ----------------
// HC written TRANSPOSED: HC[(blk*DS + n)*D + d]. Direct coalesced stores (r11).
__global__ __launch_bounds__(128) void k_scanA(
    const __bf16* __restrict__ DTbf, const __bf16* __restrict__ XCCbf,
    const float* __restrict__ BCb, const float* __restrict__ Alog_l,
    float* __restrict__ HC, float* __restrict__ DTS)
{
  __shared__ float Bs[CT][DS];     // 2 KB
  __shared__ __bf16 DTs[CT][128];  // 8 KB
  __shared__ __bf16 XCs[CT][128];  // 8 KB
  int blk = blockIdx.x;
  int c  = blk % NC;
  int rb = blk / NC;
  int rdir = rb / B;
  int d = threadIdx.x;
  int s0 = c * CT;
  int cn = min(CT, L - s0);
  size_t rowbase = (size_t)rb * L + s0;

  // batched staging loads
  int totB = cn * DS;
  float bb[4]; bool bp[4];
#pragma unroll
  for (int i = 0; i < 4; ++i) {
    int q = d + i * 128;
    bp[i] = q < totB;
    bb[i] = bp[i] ? BCb[(rowbase + (q >> 4)) * 32 + (q & 15)] : 0.f;
  }
  int totD = cn * 16;
  int4 dv[4], xv[4]; bool dp[4];
#pragma unroll
  for (int i = 0; i < 4; ++i) {
    int q = d + i * 128;
    dp[i] = q < totD;
    dv[i] = make_int4(0, 0, 0, 0);
    xv[i] = make_int4(0, 0, 0, 0);
    int row = q >> 4, c8 = (q & 15) * 8;
    if (dp[i]) {
      dv[i] = *(const int4*)(DTbf + (rowbase + row) * D + c8);
      xv[i] = *(const int4*)(XCCbf + (rowbase + row) * D + c8);
    }
  }
  float An[DS];
  const float* Ab = Alog_l + (size_t)rdir * D * DS + (size_t)d * DS;
#pragma unroll
  for (int n = 0; n < DS; ++n) An[n] = -__expf(Ab[n]);
  bool fast = an_is_linear(An);
  // LDS writes after all loads issued
#pragma unroll
  for (int i = 0; i < 4; ++i) {
    int q = d + i * 128;
    if (bp[i]) Bs[q >> 4][q & 15] = bb[i];
  }
#pragma unroll
  for (int i = 0; i < 4; ++i) {
    int q = d + i * 128;
    int row = q >> 4, c8 = (q & 15) * 8;
    if (dp[i]) {
      *(int4*)&DTs[row][c8] = dv[i];
      *(int4*)&XCs[row][c8] = xv[i];
    }
  }
  __syncthreads();
  float h[DS];
#pragma unroll
  for (int n = 0; n < DS; ++n) h[n] = 0.f;
  float dts = 0.f;
  if (fast) {
    for (int ss = 0; ss < cn; ++ss) {
      float dt = (float)DTs[ss][d];
      float xc = (float)XCs[ss][d];
      dts += dt;
      float e = dt * xc;
      float pw[DS];
      pow_tree(__expf(-dt), pw);
#pragma unroll
      for (int n = 0; n < DS; ++n)
        h[n] = fmaf(pw[n], h[n], e * Bs[ss][n]);
    }
  } else {
    for (int ss = 0; ss < cn; ++ss) {
      float dt = (float)DTs[ss][d];
      float xc = (float)XCs[ss][d];
      dts += dt;
      float e = dt * xc;
#pragma unroll
      for (int n = 0; n < DS; ++n)
        h[n] = __expf(dt * An[n]) * h[n] + e * Bs[ss][n];
    }
  }
  DTS[(size_t)blk * D + d] = dts;
  // direct coalesced [n][d] stores (fixed n: 128 consecutive floats across threads)
#pragma unroll
  for (int n = 0; n < DS; ++n)
    HC[((size_t)blk * DS + n) * D + d] = h[n];
}

// ---------------- scan phase B: boundary chain, n-parallel ----------------
__global__ __launch_bounds__(128) void k_scanB(
    const float* __restrict__ HC, const float* __restrict__ DTS,
    const float* __restrict__ Alog_l, float* __restrict__ HIN)
{
  int rb = blockIdx.x >> 4;
  int n  = blockIdx.x & 15;
  int rdir = rb / B;
  int d = threadIdx.x;
  float An_v = -__expf(Alog_l[((size_t)rdir * D + d) * DS + n]);
  float hc[8], dts[8];
#pragma unroll
  for (int k = 0; k < 8; ++k) {
    int cc = (k < NC) ? k : NC - 1;
    hc[k]  = HC[((size_t)(rb * NC + cc) * DS + n) * D + d];
    dts[k] = DTS[((size_t)(rb * NC + cc)) * D + d];
  }
  float h = 0.f;
  for (int c = 0; c < NC; c += 8) {
#pragma unroll
    for (int k = 0; k < 8; ++k) {
      int cc = c + k;
      if (cc >= NC) break;
      HIN[((size_t)(rb * NC + cc) * DS + n) * D + d] = h;
      h = __expf(dts[k] * An_v) * h + hc[k];
      int cp = cc + 8 < NC ? cc + 8 : NC - 1;
      hc[k]  = HC[((size_t)(rb * NC + cp) * DS + n) * D + d];
      dts[k] = DTS[((size_t)(rb * NC + cp)) * D + d];
    }
  }
}

// ---------------- scan phase C: LDS-staged inputs, emit y bf16 ----------------
// Staging batched; HIN/A/Dp register loads hoisted before LDS writes.
__global__ __launch_bounds__(128) void k_scanC(
    const __bf16* __restrict__ DTbf, const __bf16* __restrict__ XCCbf,
    const float* __restrict__ BCb, const __bf16* __restrict__ Zbf,
    const float* __restrict__ HIN, const float* __restrict__ Alog_l,
    const float* __restrict__ Dp_l, __bf16* __restrict__ YMbf)
{
  __shared__ float Bsm[CT][DS];
  __shared__ float Csm[CT][DS];
  __shared__ __bf16 DTs[CT][128];
  __shared__ __bf16 XCs[CT][128];
  __shared__ __bf16 Zs[CT][128];
  int blk = blockIdx.x;
  int c  = blk % NC;
  int rb = blk / NC;
  int rdir = rb / B;
  int b = rb % B;
  int d = threadIdx.x;
  int s0 = c * CT;
  int cn = min(CT, L - s0);
  size_t rowbase = (size_t)rb * L + s0;

  // batched staging loads
  int tot2 = cn * 2 * DS;
  float cbv[8]; bool cbp[8];
#pragma unroll
  for (int i = 0; i < 8; ++i) {
    int q = d + i * 128;
    cbp[i] = q < tot2;
    cbv[i] = cbp[i] ? BCb[(rowbase + (q >> 5)) * 32 + (q & 31)] : 0.f;
  }
  int totD = cn * 16;
  int4 dv[4], xv[4], zv[4]; bool dp[4];
#pragma unroll
  for (int i = 0; i < 4; ++i) {
    int q = d + i * 128;
    dp[i] = q < totD;
    dv[i] = make_int4(0, 0, 0, 0);
    xv[i] = make_int4(0, 0, 0, 0);
    zv[i] = make_int4(0, 0, 0, 0);
    int row = q >> 4, c8 = (q & 15) * 8;
    if (dp[i]) {
      dv[i] = *(const int4*)(DTbf + (rowbase + row) * D + c8);
      xv[i] = *(const int4*)(XCCbf + (rowbase + row) * D + c8);
      zv[i] = *(const int4*)(Zbf + (rowbase + row) * D + c8);
    }
  }
  float An[DS];
  const float* Ab = Alog_l + (size_t)rdir * D * DS + (size_t)d * DS;
#pragma unroll
  for (int n = 0; n < DS; ++n) An[n] = -__expf(Ab[n]);
  bool fast = an_is_linear(An);
  float h[DS];
#pragma unroll
  for (int n = 0; n < DS; ++n)
    h[n] = HIN[((size_t)blk * DS + n) * D + d];   // [n][d] layout: coalesced
  float Dpv = Dp_l[rdir * D + d];
  // LDS writes after all loads issued
#pragma unroll
  for (int i = 0; i < 8; ++i) {
    int q = d + i * 128;
    if (cbp[i]) {
      int ss = q >> 5, j = q & 31;
      if (j < DS) Bsm[ss][j] = cbv[i]; else Csm[ss][j - DS] = cbv[i];
    }
  }
#pragma unroll
  for (int i = 0; i < 4; ++i) {
    int q = d + i * 128;
    int row = q >> 4, c8 = (q & 15) * 8;
    if (dp[i]) {
      *(int4*)&DTs[row][c8] = dv[i];
      *(int4*)&XCs[row][c8] = xv[i];
      *(int4*)&Zs[row][c8]  = zv[i];
    }
  }
  __syncthreads();
  if (fast) {
    for (int ss = 0; ss < cn; ++ss) {
      float dt = (float)DTs[ss][d];
      float xc = (float)XCs[ss][d];
      float z  = (float)Zs[ss][d];
      float e = dt * xc;
      float pw[DS];
      pow_tree(__expf(-dt), pw);
      float y = xc * Dpv;
#pragma unroll
      for (int n = 0; n < DS; ++n) {
        h[n] = fmaf(pw[n], h[n], e * Bsm[ss][n]);
        y = fmaf(h[n], Csm[ss][n], y);
      }
      y *= z * sigmoidf_(z);
      int s = s0 + ss;
      int tt = rdir ? (L - 1 - s) : s;
      YMbf[((size_t)b * L + tt) * 256 + rdir * 128 + d] = (__bf16)y;
    }
  } else {
    for (int ss = 0; ss < cn; ++ss) {
      float dt = (float)DTs[ss][d];
      float xc = (float)XCs[ss][d];
      float z  = (float)Zs[ss][d];
      float e = dt * xc;
      float y = xc * Dpv;
#pragma unroll
      for (int n = 0; n < DS; ++n) {
        h[n] = __expf(dt * An[n]) * h[n] + e * Bsm[ss][n];
        y = fmaf(h[n], Csm[ss][n], y);
      }
      y *= z * sigmoidf_(z);
      int s = s0 + ss;
      int tt = rdir ? (L - 1 - s) : s;
      YMbf[((size_t)b * L + tt) * 256 + rdir * 128 + d] = (__bf16)y;
    }
  }
}

// ---------------- fused tail: outproj + LN1 + FFN1 + FFN2 + LN2 (+ final LN/out on last) ----------------
// Round-6 verified structure (register-prefetched weight panels).
__global__ __launch_bounds__(256) void k_tail(
    const __bf16* __restrict__ YMbf, const __bf16* __restrict__ Wout,
    const float* __restrict__ g1, const float* __restrict__ be1,
    const __bf16* __restrict__ w1bf, const float* __restrict__ b1,
    const __bf16* __restrict__ w2bf, const float* __restrict__ b2,
    const float* __restrict__ g2, const float* __restrict__ be2,
    float* __restrict__ U, __bf16* __restrict__ Ubf,
    int last, const float* __restrict__ lnfg, const float* __restrict__ lnfb,
    float* __restrict__ outp)
{
  __shared__ short AX[64 * KS];
  __shared__ short BH[128 * KS];
  __shared__ short Ws[64 * KS];
  int m0 = blockIdx.x * 64;
  int tid = threadIdx.x;
  int wave = tid >> 6, lane = tid & 63, lm = lane & 15, lq = lane >> 4;
  int rr0 = tid >> 4, gcol = tid & 15;
  f32x4 zero4 = {0.f, 0.f, 0.f, 0.f};

  // ---- preload U rows for LN1 (latency hides under phase 1) ----
  float uvp[4][8];
#pragma unroll
  for (int r = 0; r < 4; ++r) {
    int row = m0 + wave * 16 + lq * 4 + r;
    bool valid = row < BL;
#pragma unroll
    for (int c = 0; c < 8; ++c) {
      int col = c * 16 + lm;
      uvp[r][c] = valid ? U[(size_t)row * 128 + col] : 0.f;
    }
  }

  // ---- phase 1: outproj (K=256) ----
  int4 w1v0[4], w1v1[4], w1v2[4], w1v3[4];
  f32x4 acc[8];
#pragma unroll
  for (int c = 0; c < 8; ++c) acc[c] = zero4;
#pragma unroll
  for (int kc = 0; kc < 2; ++kc) {
    if (kc) __syncthreads();
    {
      int4 ymv[4];
#pragma unroll
      for (int j = 0; j < 4; ++j) {
        int m = m0 + rr0 + j * 16;
        ymv[j] = make_int4(0, 0, 0, 0);
        if (m < BL) ymv[j] = *(const int4*)(YMbf + (size_t)m * 256 + kc * 128 + gcol * 8);
      }
      int4 wov[8];
#pragma unroll
      for (int j = 0; j < 8; ++j)
        wov[j] = *(const int4*)(Wout + (size_t)(rr0 + j * 16) * 256 + kc * 128 + gcol * 8);
#pragma unroll
      for (int j = 0; j < 4; ++j)
        *(int4*)&AX[(rr0 + j * 16) * KS + gcol * 8] = ymv[j];
#pragma unroll
      for (int j = 0; j < 8; ++j)
        *(int4*)&BH[(rr0 + j * 16) * KS + gcol * 8] = wov[j];
    }
    if (kc == 1) {
      // prefetch all 4 w1 panels into regs (consumed in FFN1 stage writes)
#pragma unroll
      for (int j = 0; j < 4; ++j)
        w1v0[j] = *(const int4*)(w1bf + (size_t)(0 * 64 + rr0 + j * 16) * 128 + gcol * 8);
#pragma unroll
      for (int j = 0; j < 4; ++j)
        w1v1[j] = *(const int4*)(w1bf + (size_t)(1 * 64 + rr0 + j * 16) * 128 + gcol * 8);
#pragma unroll
      for (int j = 0; j < 4; ++j)
        w1v2[j] = *(const int4*)(w1bf + (size_t)(2 * 64 + rr0 + j * 16) * 128 + gcol * 8);
#pragma unroll
      for (int j = 0; j < 4; ++j)
        w1v3[j] = *(const int4*)(w1bf + (size_t)(3 * 64 + rr0 + j * 16) * 128 + gcol * 8);
    }
    __syncthreads();
    for (int ks = 0; ks < 128; ks += 32) {
      bf16x8 af = *(const bf16x8*)&AX[(wave * 16 + lm) * KS + ks + lq * 8];
#pragma unroll
      for (int c = 0; c < 8; ++c) {
        bf16x8 bfr = *(const bf16x8*)&BH[(c * 16 + lm) * KS + ks + lq * 8];
        acc[c] = __builtin_amdgcn_mfma_f32_16x16x32_bf16(af, bfr, acc[c], 0, 0, 0);
      }
    }
  }
  __syncthreads();

  // ---- phase 2: residual + LN1 -> XRbf in AX ----
  {
    float g1c[8], be1c[8];
#pragma unroll
    for (int c = 0; c < 8; ++c) {
      int col = c * 16 + lm;
      g1c[c] = g1[col]; be1c[c] = be1[col];
    }
#pragma unroll
    for (int r = 0; r < 4; ++r) {
      float os[8];
      float sum = 0.f;
#pragma unroll
      for (int c = 0; c < 8; ++c) {
        os[c] = acc[c][r] + uvp[r][c];
        sum += os[c];
      }
#pragma unroll
      for (int mm = 1; mm < 16; mm <<= 1) sum += __shfl_xor(sum, mm, 64);
      float mean = sum * (1.f / 128.f);
      float qv = 0.f;
#pragma unroll
      for (int c = 0; c < 8; ++c) { float dv = os[c] - mean; qv += dv * dv; }
#pragma unroll
      for (int mm = 1; mm < 16; mm <<= 1) qv += __shfl_xor(qv, mm, 64);
      float inv = rsqrtf(qv * (1.f / 128.f) + 1e-5f);
      int rl = wave * 16 + lq * 4 + r;
#pragma unroll
      for (int c = 0; c < 8; ++c) {
        int col = c * 16 + lm;
        float o = (os[c] - mean) * inv * g1c[c] + be1c[c];
        AX[rl * KS + col] = (short)__builtin_bit_cast(unsigned short, (__bf16)o);
      }
    }
  }

  // ---- phase 3: FFN1 (K=128), H -> BH ----
  int4 w2v0[4], w2v1[4], w2v2[4], w2v3[4];
#pragma unroll
  for (int cc = 0; cc < 4; ++cc) {
    __syncthreads();
#pragma unroll
    for (int j = 0; j < 4; ++j) {
      int4 wv = (cc == 0) ? w1v0[j] : (cc == 1) ? w1v1[j] : (cc == 2) ? w1v2[j] : w1v3[j];
      *(int4*)&Ws[(rr0 + j * 16) * KS + gcol * 8] = wv;
    }
    if (cc == 3) {
      // prefetch all 4 w2 panels (ph = nc*2+kc)
#pragma unroll
      for (int j = 0; j < 4; ++j)
        w2v0[j] = *(const int4*)(w2bf + (size_t)(0 * 64 + rr0 + j * 16) * 256 + 0 * 128 + gcol * 8);
#pragma unroll
      for (int j = 0; j < 4; ++j)
        w2v1[j] = *(const int4*)(w2bf + (size_t)(0 * 64 + rr0 + j * 16) * 256 + 1 * 128 + gcol * 8);
#pragma unroll
      for (int j = 0; j < 4; ++j)
        w2v2[j] = *(const int4*)(w2bf + (size_t)(1 * 64 + rr0 + j * 16) * 256 + 0 * 128 + gcol * 8);
#pragma unroll
      for (int j = 0; j < 4; ++j)
        w2v3[j] = *(const int4*)(w2bf + (size_t)(1 * 64 + rr0 + j * 16) * 256 + 1 * 128 + gcol * 8);
    }
    __syncthreads();
    f32x4 a1[4];
#pragma unroll
    for (int c = 0; c < 4; ++c) a1[c] = zero4;
    for (int ks = 0; ks < 128; ks += 32) {
      bf16x8 af = *(const bf16x8*)&AX[(wave * 16 + lm) * KS + ks + lq * 8];
#pragma unroll
      for (int c = 0; c < 4; ++c) {
        bf16x8 bfr = *(const bf16x8*)&Ws[(c * 16 + lm) * KS + ks + lq * 8];
        a1[c] = __builtin_amdgcn_mfma_f32_16x16x32_bf16(af, bfr, a1[c], 0, 0, 0);
      }
    }
#pragma unroll
    for (int c = 0; c < 4; ++c) {
      int col = cc * 64 + c * 16 + lm;
      float bb = b1[col];
#pragma unroll
      for (int e = 0; e < 4; ++e) {
        int rl = wave * 16 + lq * 4 + e;
        float hv = fmaxf(a1[c][e] + bb, 0.f);
        BH[rl * HS + col] = (short)__builtin_bit_cast(unsigned short, (__bf16)hv);
      }
    }
  }

  // ---- phase 4: FFN2 (K=256) + residual + LN2 (+ lnf/out on last) ----
  f32x4 a2[2][4];
#pragma unroll
  for (int nc = 0; nc < 2; ++nc)
#pragma unroll
    for (int c = 0; c < 4; ++c) a2[nc][c] = zero4;
#pragma unroll
  for (int ph = 0; ph < 4; ++ph) {       // ph = nc*2 + kc
    int nc = ph >> 1, kc = ph & 1;
    __syncthreads();
#pragma unroll
    for (int j = 0; j < 4; ++j) {
      int4 wv = (ph == 0) ? w2v0[j] : (ph == 1) ? w2v1[j] : (ph == 2) ? w2v2[j] : w2v3[j];
      *(int4*)&Ws[(rr0 + j * 16) * KS + gcol * 8] = wv;
    }
    __syncthreads();
    for (int ks = 0; ks < 128; ks += 32) {
      bf16x8 af = *(const bf16x8*)&BH[(wave * 16 + lm) * HS + kc * 128 + ks + lq * 8];
#pragma unroll
      for (int c = 0; c < 4; ++c) {
        bf16x8 bfr = *(const bf16x8*)&Ws[(c * 16 + lm) * KS + ks + lq * 8];
        a2[nc][c] = __builtin_amdgcn_mfma_f32_16x16x32_bf16(af, bfr, a2[nc][c], 0, 0, 0);
      }
    }
  }
  {
    float b2c[8], g2c[8], be2c[8];
#pragma unroll
    for (int q = 0; q < 8; ++q) {
      int col = (q >> 2) * 64 + (q & 3) * 16 + lm;
      b2c[q] = b2[col]; g2c[q] = g2[col]; be2c[q] = be2[col];
    }
#pragma unroll
    for (int r = 0; r < 4; ++r) {
      int rl = wave * 16 + lq * 4 + r;
      int row = m0 + rl;
      bool valid = row < BL;
      float os[8];
      float sum = 0.f;
#pragma unroll
      for (int q = 0; q < 8; ++q) {
        int nc = q >> 2, c = q & 3;
        int col = nc * 64 + c * 16 + lm;
        __bf16 xb = __builtin_bit_cast(__bf16, (unsigned short)AX[rl * KS + col]);
        os[q] = a2[nc][c][r] + b2c[q] + (float)xb;
        sum += os[q];
      }
#pragma unroll
      for (int mm = 1; mm < 16; mm <<= 1) sum += __shfl_xor(sum, mm, 64);
      float mean = sum * (1.f / 128.f);
      float qv = 0.f;
#pragma unroll
      for (int q = 0; q < 8; ++q) { float dv = os[q] - mean; qv += dv * dv; }
#pragma unroll
      for (int mm = 1; mm < 16; mm <<= 1) qv += __shfl_xor(qv, mm, 64);
      float inv = rsqrtf(qv * (1.f / 128.f) + 1e-5f);
      float o[8];
#pragma unroll
      for (int q = 0; q < 8; ++q)
        o[q] = (os[q] - mean) * inv * g2c[q] + be2c[q];
      if (!last) {
        if (valid) {
#pragma unroll
          for (int q = 0; q < 8; ++q) {
            int col = (q >> 2) * 64 + (q & 3) * 16 + lm;
            U[(size_t)row * 128 + col] = o[q];
          }
        }
        // Ubf routed through AX (same elements this thread just read)
#pragma unroll
        for (int q = 0; q < 8; ++q) {
          int col = (q >> 2) * 64 + (q & 3) * 16 + lm;
          AX[rl * KS + col] = (short)__builtin_bit_cast(unsigned short, (__bf16)o[q]);
        }
      } else {
        float s2 = 0.f;
#pragma unroll
        for (int q = 0; q < 8; ++q) s2 += o[q];
#pragma unroll
        for (int mm = 1; mm < 16; mm <<= 1) s2 += __shfl_xor(s2, mm, 64);
        float mean2 = s2 * (1.f / 128.f);
        float qv2 = 0.f;
#pragma unroll
        for (int q = 0; q < 8; ++q) { float dv = o[q] - mean2; qv2 += dv * dv; }
#pragma unroll
        for (int mm = 1; mm < 16; mm <<= 1) qv2 += __shfl_xor(qv2, mm, 64);
        float inv2 = rsqrtf(qv2 * (1.f / 128.f) + 1e-5f);
        if (valid) {
          int bb = row / L;
          int t = row - bb * L;
          if (t < N * P) {
            int n = t >> 7, p = t & 127;
            size_t obase = (((size_t)bb * N + n) * D) * P + p;
#pragma unroll
            for (int q = 0; q < 8; ++q) {
              int col = (q >> 2) * 64 + (q & 3) * 16 + lm;
              float o2 = (o[q] - mean2) * inv2 * lnfg[col] + lnfb[col];
              outp[obase + (size_t)col * P] = o2;
            }
          }
        }
      }
    }
  }
  if (!last) {
    __syncthreads();
    // coalesced Ubf store from AX
#pragma unroll
    for (int i = 0; i < 4; ++i) {
      int rr = rr0 + 16 * i;
      int m = m0 + rr;
      if (m < BL)
        *(int4*)(Ubf + (size_t)m * 128 + gcol * 8) = *(const int4*)&AX[rr * KS + gcol * 8];
    }
  }
}

extern "C" void kernel_launch(void* const* d_in, const int* in_sizes, int n_in,
                              void* d_out, int out_size, void* d_ws, size_t ws_size,
                              hipStream_t stream)
{
  (void)in_sizes; (void)n_in; (void)out_size; (void)ws_size;
  const float* x       = (const float*)d_in[0];
  const float* view    = (const float*)d_in[1];
  const float* wp_w    = (const float*)d_in[2];
  const float* wp_b    = (const float*)d_in[3];
  const float* m_in_w  = (const float*)d_in[4];
  const float* m_conv_w= (const float*)d_in[5];
  const float* m_conv_b= (const float*)d_in[6];
  const float* m_xproj = (const float*)d_in[7];
  const float* m_dt_w  = (const float*)d_in[8];
  const float* m_dt_b  = (const float*)d_in[9];
  const float* m_Alog  = (const float*)d_in[10];
  const float* m_Dp    = (const float*)d_in[11];
  const float* m_out_w = (const float*)d_in[12];
  const float* ffn_w1  = (const float*)d_in[13];
  const float* ffn_b1  = (const float*)d_in[14];
  const float* ffn_w2  = (const float*)d_in[15];
  const float* ffn_b2  = (const float*)d_in[16];
  const float* ln1_g   = (const float*)d_in[17];
  const float* ln1_b   = (const float*)d_in[18];
  const float* ln2_g   = (const float*)d_in[19];
  const float* ln2_b   = (const float*)d_in[20];
  const float* lnf_g   = (const float*)d_in[21];
  const float* lnf_b   = (const float*)d_in[22];
  float* out = (float*)d_out;

  float* W = (float*)d_ws;
  size_t off = 0;
  auto alloc = [&](size_t nfl) { float* p = W + off; off += (nfl + 3) & ~(size_t)3; return p; };
  float* U      = alloc((size_t)BL * D);
  float* Ubf_f  = alloc((size_t)BL * D / 2);
  float* XCC_f  = alloc((size_t)BL * D);          // 2*BL*D bf16
  float* Zbf_f  = alloc((size_t)BL * D);          // 2*BL*D bf16
  float* DT_f   = alloc((size_t)BL * D);          // 2*BL*D bf16
  float* BCb    = alloc((size_t)2 * BL * 2 * DS);
  float* YM_f   = alloc((size_t)BL * 256 / 2);
  float* HC     = alloc((size_t)2 * B * NC * D * DS);
  float* DTS    = alloc((size_t)2 * B * NC * D);
  float* HIN    = alloc((size_t)2 * B * NC * D * DS);
  float* weff_f = alloc(262144 / 2);
  float* xpw_f  = alloc(20480 / 2);
  float* outw_f = alloc(65536 / 2);
  float* w1_f   = alloc(65536 / 2);
  float* w2_f   = alloc(65536 / 2);

  __bf16* Ubf    = (__bf16*)Ubf_f;
  __bf16* XCCbf  = (__bf16*)XCC_f;
  __bf16* Zbf    = (__bf16*)Zbf_f;
  __bf16* DTbf   = (__bf16*)DT_f;
  __bf16* YMbf   = (__bf16*)YM_f;
  __bf16* weff   = (__bf16*)weff_f;
  __bf16* xpw_bf = (__bf16*)xpw_f;
  __bf16* outw_bf= (__bf16*)outw_f;
  __bf16* w1_bf  = (__bf16*)w1_f;
  __bf16* w2_bf  = (__bf16*)w2_f;

  k_init<<<PREP_BLOCKS + EMBED_BLOCKS, 256, 0, stream>>>(
      m_in_w, m_conv_w, m_xproj, m_out_w, ffn_w1, ffn_w2,
      weff, xpw_bf, outw_bf, w1_bf, w2_bf,
      x, view, wp_w, wp_b, U, Ubf);

  for (int l = 0; l < EL; ++l) {
    const float* conv_b_l = m_conv_b + (size_t)l * 2 * D;
    const float* dt_w_l   = m_dt_w   + (size_t)l * 2 * D * DTR;
    const float* dt_b_l   = m_dt_b   + (size_t)l * 2 * D;
    const float* Alog_l   = m_Alog   + (size_t)l * 2 * D * DS;
    const float* Dp_l     = m_Dp     + (size_t)l * 2 * D;

    k_front <<<dim3(2 * MT64, 2), 256, 0, stream>>>(
        Ubf, weff + (size_t)l * 2 * 256 * 256, conv_b_l,
        xpw_bf + (size_t)l * 2 * 40 * 128, dt_w_l, dt_b_l,
        XCCbf, Zbf, BCb, DTbf);
    k_scanA <<<2 * B * NC, 128, 0, stream>>>(DTbf, XCCbf, BCb, Alog_l, HC, DTS);
    k_scanB <<<2 * B * 16, 128, 0, stream>>>(HC, DTS, Alog_l, HIN);
    k_scanC <<<2 * B * NC, 128, 0, stream>>>(DTbf, XCCbf, BCb, Zbf, HIN, Alog_l, Dp_l, YMbf);
    k_tail  <<<MT64, 256, 0, stream>>>(
        YMbf, outw_bf + (size_t)l * 128 * 256,
        ln1_g + l * D, ln1_b + l * D,
        w1_bf + (size_t)l * 256 * 128, ffn_b1 + l * DFF,
        w2_bf + (size_t)l * 128 * 256, ffn_b2 + l * D,
        ln2_g + l * D, ln2_b + l * D, U, Ubf,
        (l == EL - 1) ? 1 : 0, lnf_g, lnf_b, out);
  }
}

// Round 16
// 275.947 us; speedup vs baseline: 1.2646x; 1.0148x over previous
//
#include <hip/hip_runtime.h>
#include <hip/hip_bf16.h>
#include <math.h>

#define DEV __device__ __forceinline__

constexpr int B  = 8,  N = 16, P = 128, PL = 16;
constexpr int D  = 128, DS = 16, DTR = 8, DFF = 256, EL = 2;
constexpr int L  = N * P + 1;            // 2049
constexpr int BL = B * L;                // 16392
constexpr int CT = 32;                   // scan chunk length (32: verified best)
constexpr int NC = (L + CT - 1) / CT;    // 65
constexpr int MT64  = (BL + 63) / 64;    // 257
constexpr int KS = 136;                  // LDS row stride (bf16/short units)
constexpr int HS = 264;                  // LDS row stride for H (256+8)
constexpr int PREP_BLOCKS  = 1872;
constexpr int EMBED_BLOCKS = (BL * D + 255) / 256;  // 8196

using bf16x8 = __attribute__((ext_vector_type(8))) __bf16;
using f32x4  = __attribute__((ext_vector_type(4))) float;
using i32x4  = __attribute__((ext_vector_type(4))) int;

DEV float sigmoidf_(float x) { return 1.0f / (1.0f + __expf(-x)); }

// r^(n+1) for n=0..15, depth-4 tree
DEV void pow_tree(float r, float* pw) {
  float r2 = r * r;
  float r3 = r2 * r;
  float r4 = r2 * r2;
  float r8 = r4 * r4;
  float r12 = r8 * r4;
  pw[0] = r;       pw[1] = r2;      pw[2] = r3;      pw[3] = r4;
  pw[4] = r4 * r;  pw[5] = r4 * r2; pw[6] = r4 * r3; pw[7] = r8;
  pw[8] = r8 * r;  pw[9] = r8 * r2; pw[10] = r8 * r3; pw[11] = r12;
  pw[12] = r12 * r; pw[13] = r12 * r2; pw[14] = r12 * r3; pw[15] = r12 * r4;
}

// A_n check: A_init = log(1..16) broadcast -> A_n = -(n+1) exactly.
DEV bool an_is_linear(const float* An) {
  bool ok = true;
#pragma unroll
  for (int n = 0; n < DS; ++n)
    ok = ok && (fabsf(An[n] + (float)(n + 1)) < 1e-3f * (n + 1));
  return ok;
}

// ---------------- merged init: weight prep (blocks 0..1871) + patch embed ----------------
__global__ __launch_bounds__(256) void k_init(
    const float* __restrict__ in_w, const float* __restrict__ conv_w,
    const float* __restrict__ xproj, const float* __restrict__ out_w,
    const float* __restrict__ w1, const float* __restrict__ w2,
    __bf16* __restrict__ weff, __bf16* __restrict__ xpw_bf,
    __bf16* __restrict__ outw_bf, __bf16* __restrict__ w1_bf,
    __bf16* __restrict__ w2_bf,
    const float* __restrict__ x, const float* __restrict__ view,
    const float* __restrict__ wp_w, const float* __restrict__ wp_b,
    float* __restrict__ U, __bf16* __restrict__ Ubf)
{
  int bid = blockIdx.x;
  if (bid < PREP_BLOCKS) {
    int g = bid * 256 + threadIdx.x;
    if (g < 262144) {
      int l = g >> 17;
      int r = g & 131071;
      int dir = r >> 16;
      int r2 = r & 65535;
      int col = r2 >> 8;
      int kk = r2 & 255;
      int chunk = kk >> 7, k = kk & 127;
      int ld = l * 2 + dir;
      float v;
      if (col < 128) {
        v = in_w[((size_t)ld * 256 + col) * 128 + k] *
            conv_w[((size_t)ld * 128 + col) * 2 + chunk];
      } else {
        v = chunk ? in_w[((size_t)ld * 256 + col) * 128 + k] : 0.f;
      }
      weff[((size_t)ld * 256 + col) * 256 + chunk * 128 + k] = (__bf16)v;
      return;
    }
    g -= 262144;
    if (g < 20480) { xpw_bf[g] = (__bf16)xproj[g]; return; }
    g -= 20480;
    if (g < 65536) {
      int k = g & 127; int q = g >> 7; int n = q & 127; int q2 = q >> 7;
      int dir = q2 & 1; int l = q2 >> 1;
      outw_bf[((size_t)(l * 128 + n)) * 256 + dir * 128 + k] = (__bf16)out_w[g];
      return;
    }
    g -= 65536;
    if (g < 65536) { w1_bf[g] = (__bf16)w1[g]; return; }
    g -= 65536;
    if (g < 65536) { w2_bf[g] = (__bf16)w2[g]; return; }
    return;
  }
  // embed part
  int g = (bid - PREP_BLOCKS) * 256 + threadIdx.x;
  if (g >= BL * D) return;
  int d = g & (D - 1);
  int row = g >> 7;
  int b = row / L, t = row % L;
  float acc;
  if (t < N * P) {
    const float* xr = x + ((size_t)b * N * P + t) * PL;
    acc = wp_b[d];
#pragma unroll
    for (int k = 0; k < PL; ++k) acc += xr[k] * wp_w[d * PL + k];
  } else {
    acc = view[b * D + d];
  }
  U[(size_t)row * D + d] = acc;
  Ubf[(size_t)row * D + d] = (__bf16)acc;
}

// ---------------- fused front: xz GEMM + conv + silu + xproj + dt ----------------
// Staging loops batched (round-5). dt softplus uses fast __logf (round-10).
// W panels register-prefetched at kernel start (round-11).
__global__ __launch_bounds__(256) void k_front(
    const __bf16* __restrict__ Ubf, const __bf16* __restrict__ Weff,
    const float* __restrict__ conv_b_l, const __bf16* __restrict__ xpw,
    const float* __restrict__ dt_w_l, const float* __restrict__ dt_b_l,
    __bf16* __restrict__ XCCbf, __bf16* __restrict__ Zbf,
    float* __restrict__ BCb, __bf16* __restrict__ DTbf)
{
  __shared__ short As[64 * KS];    // 17408 B : U staging -> later xc bf16
  __shared__ short Ws[64 * KS];    // 17408 B : weight staging
  __shared__ float dbs[64][9];     //  2304 B
  int bx = blockIdx.x;
  int rdir = bx / MT64;
  int tile = bx % MT64;
  bool isx = (blockIdx.y == 0);
  int tid = threadIdx.x;
  int m0 = tile * 64;
  const __bf16* Wb = Weff + (size_t)rdir * 256 * 256;
  int wave = tid >> 6, lane = tid & 63, lm = lane & 15, lq = lane >> 4;
  int rr0 = tid >> 4, gcol = tid & 15;
  int kc0 = isx ? 0 : 1;
  int colx = isx ? 0 : 128;

  // ---- prefetch W panels into regs (phase pidx = (kc-kc0)*2+ch) ----
  int4 wpA[4], wpB[4], wpC[4], wpD[4];
#pragma unroll
  for (int j = 0; j < 4; ++j)
    wpA[j] = *(const int4*)(Wb + (size_t)(colx + 0 * 64 + rr0 + 16 * j) * 256 + kc0 * 128 + gcol * 8);
#pragma unroll
  for (int j = 0; j < 4; ++j)
    wpB[j] = *(const int4*)(Wb + (size_t)(colx + 1 * 64 + rr0 + 16 * j) * 256 + kc0 * 128 + gcol * 8);
  if (isx) {
#pragma unroll
    for (int j = 0; j < 4; ++j)
      wpC[j] = *(const int4*)(Wb + (size_t)(colx + 0 * 64 + rr0 + 16 * j) * 256 + 128 + gcol * 8);
#pragma unroll
    for (int j = 0; j < 4; ++j)
      wpD[j] = *(const int4*)(Wb + (size_t)(colx + 1 * 64 + rr0 + 16 * j) * 256 + 128 + gcol * 8);
  }

  // per-thread A-row precompute (4 rows, one 16B column-group each)
  int aoff[4];
  unsigned vmask = 0, smask = 0;
  int shif = rdir ? 128 : -128;     // element delta for kc=0 (shifted row)
#pragma unroll
  for (int i = 0; i < 4; ++i) {
    int rr = rr0 + 16 * i;
    int m = m0 + rr;
    aoff[i] = 0;
    if (m < BL) {
      int b = m / L, s = m - b * L;
      int idx1 = rdir ? (L - 1 - s) : s;
      aoff[i] = (b * L + idx1) * 128 + gcol * 8;
      vmask |= 1u << i;
      if (s >= 1) smask |= 1u << i;
    }
  }

  f32x4 zero4 = {0.f, 0.f, 0.f, 0.f};
  f32x4 acc[8];
#pragma unroll
  for (int c = 0; c < 8; ++c) acc[c] = zero4;

  for (int kc = kc0; kc < 2; ++kc) {
    if (kc != kc0) __syncthreads();
    // stage A (64 rows): batch loads -> writes
    {
      int4 av[4];
#pragma unroll
      for (int i = 0; i < 4; ++i) {
        av[i] = make_int4(0, 0, 0, 0);
        bool ok = (vmask >> i) & 1;
        if (kc == 0) ok = ok && ((smask >> i) & 1);
        if (ok) av[i] = *(const int4*)(Ubf + aoff[i] + (kc == 0 ? shif : 0));
      }
#pragma unroll
      for (int i = 0; i < 4; ++i)
        *(int4*)&As[(rr0 + 16 * i) * KS + gcol * 8] = av[i];
    }
    for (int ch = 0; ch < 2; ++ch) {
      if (ch) __syncthreads();
      {
        int pidx = (kc - kc0) * 2 + ch;
#pragma unroll
        for (int i = 0; i < 4; ++i) {
          int4 wv = (pidx == 0) ? wpA[i] : (pidx == 1) ? wpB[i] : (pidx == 2) ? wpC[i] : wpD[i];
          *(int4*)&Ws[(rr0 + 16 * i) * KS + gcol * 8] = wv;
        }
      }
      __syncthreads();
      for (int ks = 0; ks < 128; ks += 32) {
        bf16x8 af = *(const bf16x8*)&As[(wave * 16 + lm) * KS + ks + lq * 8];
#pragma unroll
        for (int c = 0; c < 4; ++c) {
          bf16x8 bfr = *(const bf16x8*)&Ws[(c * 16 + lm) * KS + ks + lq * 8];
          acc[ch * 4 + c] = __builtin_amdgcn_mfma_f32_16x16x32_bf16(af, bfr, acc[ch * 4 + c], 0, 0, 0);
        }
      }
    }
  }

  if (!isx) {
    // z epilogue: direct scatter stores
#pragma unroll
    for (int cg = 0; cg < 8; ++cg) {
      int col = cg * 16 + lm;
#pragma unroll
      for (int e = 0; e < 4; ++e) {
        int m = m0 + wave * 16 + lq * 4 + e;
        if (m < BL)
          Zbf[((size_t)rdir * BL + m) * 128 + col] = (__bf16)acc[cg][e];
      }
    }
    return;
  }

  // x epilogue: conv bias + silu -> scatter XCC store + xc bf16 into As (wave-private rows)
  __syncthreads();   // all MFMA reads of As/Ws done
#pragma unroll
  for (int cg = 0; cg < 8; ++cg) {
    int col = cg * 16 + lm;
    float cb = conv_b_l[rdir * 128 + col];
#pragma unroll
    for (int e = 0; e < 4; ++e) {
      int rl = wave * 16 + lq * 4 + e;
      int m = m0 + rl;
      float v = acc[cg][e] + cb;
      float o = v * sigmoidf_(v);
      __bf16 ob = (__bf16)o;
      if (m < BL) XCCbf[((size_t)rdir * BL + m) * 128 + col] = ob;
      As[rl * KS + col] = (short)__builtin_bit_cast(unsigned short, ob);
    }
  }
  // stage xpw (Ws safe: barrier above) — batched
  {
    int4 xv[3];
#pragma unroll
    for (int i = 0; i < 3; ++i) {
      int rr = rr0 + 16 * i;
      xv[i] = make_int4(0, 0, 0, 0);
      if (rr < 40) xv[i] = *(const int4*)(xpw + ((size_t)rdir * 40 + rr) * 128 + gcol * 8);
    }
#pragma unroll
    for (int i = 0; i < 3; ++i)
      *(int4*)&Ws[(rr0 + 16 * i) * KS + gcol * 8] = xv[i];
  }
  __syncthreads();
  // ---- xproj over LDS-resident xc ----
  f32x4 acc2[3];
#pragma unroll
  for (int c = 0; c < 3; ++c) acc2[c] = zero4;
  for (int ks = 0; ks < 128; ks += 32) {
    bf16x8 af = *(const bf16x8*)&As[(wave * 16 + lm) * KS + ks + lq * 8];
#pragma unroll
    for (int c = 0; c < 3; ++c) {
      bf16x8 bfr = *(const bf16x8*)&Ws[(c * 16 + lm) * KS + ks + lq * 8];
      acc2[c] = __builtin_amdgcn_mfma_f32_16x16x32_bf16(af, bfr, acc2[c], 0, 0, 0);
    }
  }
#pragma unroll
  for (int c = 0; c < 3; ++c) {
    int col = c * 16 + lm;
#pragma unroll
    for (int e = 0; e < 4; ++e) {
      int rl = wave * 16 + lq * 4 + e;
      int m = m0 + rl;
      float v = acc2[c][e];
      if (col < DTR) dbs[rl][col] = v;
      else if (col < DTR + 2 * DS && m < BL)
        BCb[((size_t)rdir * BL + m) * 32 + (col - DTR)] = v;
    }
  }
  __syncthreads();
  {
    int dloc = tid & 127;
    int rpar = tid >> 7;
    const float* dw = dt_w_l + ((size_t)rdir * 128 + dloc) * 8;
    float dwr[8];
#pragma unroll
    for (int j = 0; j < 8; ++j) dwr[j] = dw[j];
    float db = dt_b_l[rdir * 128 + dloc];
    for (int rr = rpar; rr < 64; rr += 2) {
      int m = m0 + rr;
      if (m >= BL) break;
      float a = db;
#pragma unroll
      for (int j = 0; j < 8; ++j) a = fmaf(dbs[rr][j], dwr[j], a);
      // softplus: fast __logf (result rounded to bf16; a>20 clamp guards overflow)
      float dtv = (a > 20.f) ? a : __logf(1.f + __expf(a));
      DTbf[((size_t)rdir * BL + m) * 128 + dloc] = (__bf16)dtv;
    }
  }
}

// ---------------- scan phase A: LDS-staged inputs (bf16 DT) ----------------
// HC written TRANSPOSED: HC[(blk*DS + n)*D + d]. Direct coalesced stores (r11).
__global__ __launch_bounds__(128) void k_scanA(
    const __bf16* __restrict__ DTbf, const __bf16* __restrict__ XCCbf,
    const float* __restrict__ BCb, const float* __restrict__ Alog_l,
    float* __restrict__ HC, float* __restrict__ DTS)
{
  __shared__ float Bs[CT][DS];     // 2 KB
  __shared__ __bf16 DTs[CT][128];  // 8 KB
  __shared__ __bf16 XCs[CT][128];  // 8 KB
  int blk = blockIdx.x;
  int c  = blk % NC;
  int rb = blk / NC;
  int rdir = rb / B;
  int d = threadIdx.x;
  int s0 = c * CT;
  int cn = min(CT, L - s0);
  size_t rowbase = (size_t)rb * L + s0;

  // batched staging loads
  int totB = cn * DS;
  float bb[4]; bool bp[4];
#pragma unroll
  for (int i = 0; i < 4; ++i) {
    int q = d + i * 128;
    bp[i] = q < totB;
    bb[i] = bp[i] ? BCb[(rowbase + (q >> 4)) * 32 + (q & 15)] : 0.f;
  }
  int totD = cn * 16;
  int4 dv[4], xv[4]; bool dp[4];
#pragma unroll
  for (int i = 0; i < 4; ++i) {
    int q = d + i * 128;
    dp[i] = q < totD;
    dv[i] = make_int4(0, 0, 0, 0);
    xv[i] = make_int4(0, 0, 0, 0);
    int row = q >> 4, c8 = (q & 15) * 8;
    if (dp[i]) {
      dv[i] = *(const int4*)(DTbf + (rowbase + row) * D + c8);
      xv[i] = *(const int4*)(XCCbf + (rowbase + row) * D + c8);
    }
  }
  float An[DS];
  const float* Ab = Alog_l + (size_t)rdir * D * DS + (size_t)d * DS;
#pragma unroll
  for (int n = 0; n < DS; ++n) An[n] = -__expf(Ab[n]);
  bool fast = an_is_linear(An);
  // LDS writes after all loads issued
#pragma unroll
  for (int i = 0; i < 4; ++i) {
    int q = d + i * 128;
    if (bp[i]) Bs[q >> 4][q & 15] = bb[i];
  }
#pragma unroll
  for (int i = 0; i < 4; ++i) {
    int q = d + i * 128;
    int row = q >> 4, c8 = (q & 15) * 8;
    if (dp[i]) {
      *(int4*)&DTs[row][c8] = dv[i];
      *(int4*)&XCs[row][c8] = xv[i];
    }
  }
  __syncthreads();
  float h[DS];
#pragma unroll
  for (int n = 0; n < DS; ++n) h[n] = 0.f;
  float dts = 0.f;
  if (fast) {
    for (int ss = 0; ss < cn; ++ss) {
      float dt = (float)DTs[ss][d];
      float xc = (float)XCs[ss][d];
      dts += dt;
      float e = dt * xc;
      float pw[DS];
      pow_tree(__expf(-dt), pw);
#pragma unroll
      for (int n = 0; n < DS; ++n)
        h[n] = fmaf(pw[n], h[n], e * Bs[ss][n]);
    }
  } else {
    for (int ss = 0; ss < cn; ++ss) {
      float dt = (float)DTs[ss][d];
      float xc = (float)XCs[ss][d];
      dts += dt;
      float e = dt * xc;
#pragma unroll
      for (int n = 0; n < DS; ++n)
        h[n] = __expf(dt * An[n]) * h[n] + e * Bs[ss][n];
    }
  }
  DTS[(size_t)blk * D + d] = dts;
  // direct coalesced [n][d] stores (fixed n: 128 consecutive floats across threads)
#pragma unroll
  for (int n = 0; n < DS; ++n)
    HC[((size_t)blk * DS + n) * D + d] = h[n];
}

// ---------------- scan phase B: boundary chain, n-parallel ----------------
__global__ __launch_bounds__(128) void k_scanB(
    const float* __restrict__ HC, const float* __restrict__ DTS,
    const float* __restrict__ Alog_l, float* __restrict__ HIN)
{
  int rb = blockIdx.x >> 4;
  int n  = blockIdx.x & 15;
  int rdir = rb / B;
  int d = threadIdx.x;
  float An_v = -__expf(Alog_l[((size_t)rdir * D + d) * DS + n]);
  float hc[8], dts[8];
#pragma unroll
  for (int k = 0; k < 8; ++k) {
    int cc = (k < NC) ? k : NC - 1;
    hc[k]  = HC[((size_t)(rb * NC + cc) * DS + n) * D + d];
    dts[k] = DTS[((size_t)(rb * NC + cc)) * D + d];
  }
  float h = 0.f;
  for (int c = 0; c < NC; c += 8) {
#pragma unroll
    for (int k = 0; k < 8; ++k) {
      int cc = c + k;
      if (cc >= NC) break;
      HIN[((size_t)(rb * NC + cc) * DS + n) * D + d] = h;
      h = __expf(dts[k] * An_v) * h + hc[k];
      int cp = cc + 8 < NC ? cc + 8 : NC - 1;
      hc[k]  = HC[((size_t)(rb * NC + cp) * DS + n) * D + d];
      dts[k] = DTS[((size_t)(rb * NC + cp)) * D + d];
    }
  }
}

// ---------------- scan phase C: LDS-staged inputs, emit y bf16 ----------------
// Staging batched; HIN/A/Dp register loads hoisted before LDS writes.
__global__ __launch_bounds__(128) void k_scanC(
    const __bf16* __restrict__ DTbf, const __bf16* __restrict__ XCCbf,
    const float* __restrict__ BCb, const __bf16* __restrict__ Zbf,
    const float* __restrict__ HIN, const float* __restrict__ Alog_l,
    const float* __restrict__ Dp_l, __bf16* __restrict__ YMbf)
{
  __shared__ float Bsm[CT][DS];
  __shared__ float Csm[CT][DS];
  __shared__ __bf16 DTs[CT][128];
  __shared__ __bf16 XCs[CT][128];
  __shared__ __bf16 Zs[CT][128];
  int blk = blockIdx.x;
  int c  = blk % NC;
  int rb = blk / NC;
  int rdir = rb / B;
  int b = rb % B;
  int d = threadIdx.x;
  int s0 = c * CT;
  int cn = min(CT, L - s0);
  size_t rowbase = (size_t)rb * L + s0;

  // batched staging loads
  int tot2 = cn * 2 * DS;
  float cbv[8]; bool cbp[8];
#pragma unroll
  for (int i = 0; i < 8; ++i) {
    int q = d + i * 128;
    cbp[i] = q < tot2;
    cbv[i] = cbp[i] ? BCb[(rowbase + (q >> 5)) * 32 + (q & 31)] : 0.f;
  }
  int totD = cn * 16;
  int4 dv[4], xv[4], zv[4]; bool dp[4];
#pragma unroll
  for (int i = 0; i < 4; ++i) {
    int q = d + i * 128;
    dp[i] = q < totD;
    dv[i] = make_int4(0, 0, 0, 0);
    xv[i] = make_int4(0, 0, 0, 0);
    zv[i] = make_int4(0, 0, 0, 0);
    int row = q >> 4, c8 = (q & 15) * 8;
    if (dp[i]) {
      dv[i] = *(const int4*)(DTbf + (rowbase + row) * D + c8);
      xv[i] = *(const int4*)(XCCbf + (rowbase + row) * D + c8);
      zv[i] = *(const int4*)(Zbf + (rowbase + row) * D + c8);
    }
  }
  float An[DS];
  const float* Ab = Alog_l + (size_t)rdir * D * DS + (size_t)d * DS;
#pragma unroll
  for (int n = 0; n < DS; ++n) An[n] = -__expf(Ab[n]);
  bool fast = an_is_linear(An);
  float h[DS];
#pragma unroll
  for (int n = 0; n < DS; ++n)
    h[n] = HIN[((size_t)blk * DS + n) * D + d];   // [n][d] layout: coalesced
  float Dpv = Dp_l[rdir * D + d];
  // LDS writes after all loads issued
#pragma unroll
  for (int i = 0; i < 8; ++i) {
    int q = d + i * 128;
    if (cbp[i]) {
      int ss = q >> 5, j = q & 31;
      if (j < DS) Bsm[ss][j] = cbv[i]; else Csm[ss][j - DS] = cbv[i];
    }
  }
#pragma unroll
  for (int i = 0; i < 4; ++i) {
    int q = d + i * 128;
    int row = q >> 4, c8 = (q & 15) * 8;
    if (dp[i]) {
      *(int4*)&DTs[row][c8] = dv[i];
      *(int4*)&XCs[row][c8] = xv[i];
      *(int4*)&Zs[row][c8]  = zv[i];
    }
  }
  __syncthreads();
  if (fast) {
    for (int ss = 0; ss < cn; ++ss) {
      float dt = (float)DTs[ss][d];
      float xc = (float)XCs[ss][d];
      float z  = (float)Zs[ss][d];
      float e = dt * xc;
      float pw[DS];
      pow_tree(__expf(-dt), pw);
      float y = xc * Dpv;
#pragma unroll
      for (int n = 0; n < DS; ++n) {
        h[n] = fmaf(pw[n], h[n], e * Bsm[ss][n]);
        y = fmaf(h[n], Csm[ss][n], y);
      }
      y *= z * sigmoidf_(z);
      int s = s0 + ss;
      int tt = rdir ? (L - 1 - s) : s;
      YMbf[((size_t)b * L + tt) * 256 + rdir * 128 + d] = (__bf16)y;
    }
  } else {
    for (int ss = 0; ss < cn; ++ss) {
      float dt = (float)DTs[ss][d];
      float xc = (float)XCs[ss][d];
      float z  = (float)Zs[ss][d];
      float e = dt * xc;
      float y = xc * Dpv;
#pragma unroll
      for (int n = 0; n < DS; ++n) {
        h[n] = __expf(dt * An[n]) * h[n] + e * Bsm[ss][n];
        y = fmaf(h[n], Csm[ss][n], y);
      }
      y *= z * sigmoidf_(z);
      int s = s0 + ss;
      int tt = rdir ? (L - 1 - s) : s;
      YMbf[((size_t)b * L + tt) * 256 + rdir * 128 + d] = (__bf16)y;
    }
  }
}

// ---------------- fused tail: outproj + LN1 + FFN1 + FFN2 + LN2 (+ final LN/out on last) ----------------
// Round-11 verified structure. Only change: streaming single-use inputs (YM
// staging, U residual preload) use __builtin_nontemporal_load so they stop
// evicting the shared Wout/w1/w2 panels from the per-XCD L2 (FETCH was 9.1 MB
// vs 0.2 MB weight working set = ~40x refetch).
__global__ __launch_bounds__(256) void k_tail(
    const __bf16* __restrict__ YMbf, const __bf16* __restrict__ Wout,
    const float* __restrict__ g1, const float* __restrict__ be1,
    const __bf16* __restrict__ w1bf, const float* __restrict__ b1,
    const __bf16* __restrict__ w2bf, const float* __restrict__ b2,
    const float* __restrict__ g2, const float* __restrict__ be2,
    float* __restrict__ U, __bf16* __restrict__ Ubf,
    int last, const float* __restrict__ lnfg, const float* __restrict__ lnfb,
    float* __restrict__ outp)
{
  __shared__ short AX[64 * KS];
  __shared__ short BH[128 * KS];
  __shared__ short Ws[64 * KS];
  int m0 = blockIdx.x * 64;
  int tid = threadIdx.x;
  int wave = tid >> 6, lane = tid & 63, lm = lane & 15, lq = lane >> 4;
  int rr0 = tid >> 4, gcol = tid & 15;
  f32x4 zero4 = {0.f, 0.f, 0.f, 0.f};

  // ---- preload U rows for LN1 (latency hides under phase 1; nontemporal) ----
  float uvp[4][8];
#pragma unroll
  for (int r = 0; r < 4; ++r) {
    int row = m0 + wave * 16 + lq * 4 + r;
    bool valid = row < BL;
#pragma unroll
    for (int c = 0; c < 8; ++c) {
      int col = c * 16 + lm;
      uvp[r][c] = valid ? __builtin_nontemporal_load(U + (size_t)row * 128 + col) : 0.f;
    }
  }

  // ---- phase 1: outproj (K=256) ----
  int4 w1v0[4], w1v1[4], w1v2[4], w1v3[4];
  f32x4 acc[8];
#pragma unroll
  for (int c = 0; c < 8; ++c) acc[c] = zero4;
#pragma unroll
  for (int kc = 0; kc < 2; ++kc) {
    if (kc) __syncthreads();
    {
      i32x4 ymv[4];
#pragma unroll
      for (int j = 0; j < 4; ++j) {
        int m = m0 + rr0 + j * 16;
        ymv[j] = (i32x4){0, 0, 0, 0};
        if (m < BL)
          ymv[j] = __builtin_nontemporal_load(
              (const i32x4*)(YMbf + (size_t)m * 256 + kc * 128 + gcol * 8));
      }
      int4 wov[8];
#pragma unroll
      for (int j = 0; j < 8; ++j)
        wov[j] = *(const int4*)(Wout + (size_t)(rr0 + j * 16) * 256 + kc * 128 + gcol * 8);
#pragma unroll
      for (int j = 0; j < 4; ++j)
        *(i32x4*)&AX[(rr0 + j * 16) * KS + gcol * 8] = ymv[j];
#pragma unroll
      for (int j = 0; j < 8; ++j)
        *(int4*)&BH[(rr0 + j * 16) * KS + gcol * 8] = wov[j];
    }
    if (kc == 1) {
      // prefetch all 4 w1 panels into regs (consumed in FFN1 stage writes)
#pragma unroll
      for (int j = 0; j < 4; ++j)
        w1v0[j] = *(const int4*)(w1bf + (size_t)(0 * 64 + rr0 + j * 16) * 128 + gcol * 8);
#pragma unroll
      for (int j = 0; j < 4; ++j)
        w1v1[j] = *(const int4*)(w1bf + (size_t)(1 * 64 + rr0 + j * 16) * 128 + gcol * 8);
#pragma unroll
      for (int j = 0; j < 4; ++j)
        w1v2[j] = *(const int4*)(w1bf + (size_t)(2 * 64 + rr0 + j * 16) * 128 + gcol * 8);
#pragma unroll
      for (int j = 0; j < 4; ++j)
        w1v3[j] = *(const int4*)(w1bf + (size_t)(3 * 64 + rr0 + j * 16) * 128 + gcol * 8);
    }
    __syncthreads();
    for (int ks = 0; ks < 128; ks += 32) {
      bf16x8 af = *(const bf16x8*)&AX[(wave * 16 + lm) * KS + ks + lq * 8];
#pragma unroll
      for (int c = 0; c < 8; ++c) {
        bf16x8 bfr = *(const bf16x8*)&BH[(c * 16 + lm) * KS + ks + lq * 8];
        acc[c] = __builtin_amdgcn_mfma_f32_16x16x32_bf16(af, bfr, acc[c], 0, 0, 0);
      }
    }
  }
  __syncthreads();

  // ---- phase 2: residual + LN1 -> XRbf in AX ----
  {
    float g1c[8], be1c[8];
#pragma unroll
    for (int c = 0; c < 8; ++c) {
      int col = c * 16 + lm;
      g1c[c] = g1[col]; be1c[c] = be1[col];
    }
#pragma unroll
    for (int r = 0; r < 4; ++r) {
      float os[8];
      float sum = 0.f;
#pragma unroll
      for (int c = 0; c < 8; ++c) {
        os[c] = acc[c][r] + uvp[r][c];
        sum += os[c];
      }
#pragma unroll
      for (int mm = 1; mm < 16; mm <<= 1) sum += __shfl_xor(sum, mm, 64);
      float mean = sum * (1.f / 128.f);
      float qv = 0.f;
#pragma unroll
      for (int c = 0; c < 8; ++c) { float dv = os[c] - mean; qv += dv * dv; }
#pragma unroll
      for (int mm = 1; mm < 16; mm <<= 1) qv += __shfl_xor(qv, mm, 64);
      float inv = rsqrtf(qv * (1.f / 128.f) + 1e-5f);
      int rl = wave * 16 + lq * 4 + r;
#pragma unroll
      for (int c = 0; c < 8; ++c) {
        int col = c * 16 + lm;
        float o = (os[c] - mean) * inv * g1c[c] + be1c[c];
        AX[rl * KS + col] = (short)__builtin_bit_cast(unsigned short, (__bf16)o);
      }
    }
  }

  // ---- phase 3: FFN1 (K=128), H -> BH ----
  int4 w2v0[4], w2v1[4], w2v2[4], w2v3[4];
#pragma unroll
  for (int cc = 0; cc < 4; ++cc) {
    __syncthreads();
#pragma unroll
    for (int j = 0; j < 4; ++j) {
      int4 wv = (cc == 0) ? w1v0[j] : (cc == 1) ? w1v1[j] : (cc == 2) ? w1v2[j] : w1v3[j];
      *(int4*)&Ws[(rr0 + j * 16) * KS + gcol * 8] = wv;
    }
    if (cc == 3) {
      // prefetch all 4 w2 panels (ph = nc*2+kc)
#pragma unroll
      for (int j = 0; j < 4; ++j)
        w2v0[j] = *(const int4*)(w2bf + (size_t)(0 * 64 + rr0 + j * 16) * 256 + 0 * 128 + gcol * 8);
#pragma unroll
      for (int j = 0; j < 4; ++j)
        w2v1[j] = *(const int4*)(w2bf + (size_t)(0 * 64 + rr0 + j * 16) * 256 + 1 * 128 + gcol * 8);
#pragma unroll
      for (int j = 0; j < 4; ++j)
        w2v2[j] = *(const int4*)(w2bf + (size_t)(1 * 64 + rr0 + j * 16) * 256 + 0 * 128 + gcol * 8);
#pragma unroll
      for (int j = 0; j < 4; ++j)
        w2v3[j] = *(const int4*)(w2bf + (size_t)(1 * 64 + rr0 + j * 16) * 256 + 1 * 128 + gcol * 8);
    }
    __syncthreads();
    f32x4 a1[4];
#pragma unroll
    for (int c = 0; c < 4; ++c) a1[c] = zero4;
    for (int ks = 0; ks < 128; ks += 32) {
      bf16x8 af = *(const bf16x8*)&AX[(wave * 16 + lm) * KS + ks + lq * 8];
#pragma unroll
      for (int c = 0; c < 4; ++c) {
        bf16x8 bfr = *(const bf16x8*)&Ws[(c * 16 + lm) * KS + ks + lq * 8];
        a1[c] = __builtin_amdgcn_mfma_f32_16x16x32_bf16(af, bfr, a1[c], 0, 0, 0);
      }
    }
#pragma unroll
    for (int c = 0; c < 4; ++c) {
      int col = cc * 64 + c * 16 + lm;
      float bb = b1[col];
#pragma unroll
      for (int e = 0; e < 4; ++e) {
        int rl = wave * 16 + lq * 4 + e;
        float hv = fmaxf(a1[c][e] + bb, 0.f);
        BH[rl * HS + col] = (short)__builtin_bit_cast(unsigned short, (__bf16)hv);
      }
    }
  }

  // ---- phase 4: FFN2 (K=256) + residual + LN2 (+ lnf/out on last) ----
  f32x4 a2[2][4];
#pragma unroll
  for (int nc = 0; nc < 2; ++nc)
#pragma unroll
    for (int c = 0; c < 4; ++c) a2[nc][c] = zero4;
#pragma unroll
  for (int ph = 0; ph < 4; ++ph) {       // ph = nc*2 + kc
    int nc = ph >> 1, kc = ph & 1;
    __syncthreads();
#pragma unroll
    for (int j = 0; j < 4; ++j) {
      int4 wv = (ph == 0) ? w2v0[j] : (ph == 1) ? w2v1[j] : (ph == 2) ? w2v2[j] : w2v3[j];
      *(int4*)&Ws[(rr0 + j * 16) * KS + gcol * 8] = wv;
    }
    __syncthreads();
    for (int ks = 0; ks < 128; ks += 32) {
      bf16x8 af = *(const bf16x8*)&BH[(wave * 16 + lm) * HS + kc * 128 + ks + lq * 8];
#pragma unroll
      for (int c = 0; c < 4; ++c) {
        bf16x8 bfr = *(const bf16x8*)&Ws[(c * 16 + lm) * KS + ks + lq * 8];
        a2[nc][c] = __builtin_amdgcn_mfma_f32_16x16x32_bf16(af, bfr, a2[nc][c], 0, 0, 0);
      }
    }
  }
  {
    float b2c[8], g2c[8], be2c[8];
#pragma unroll
    for (int q = 0; q < 8; ++q) {
      int col = (q >> 2) * 64 + (q & 3) * 16 + lm;
      b2c[q] = b2[col]; g2c[q] = g2[col]; be2c[q] = be2[col];
    }
#pragma unroll
    for (int r = 0; r < 4; ++r) {
      int rl = wave * 16 + lq * 4 + r;
      int row = m0 + rl;
      bool valid = row < BL;
      float os[8];
      float sum = 0.f;
#pragma unroll
      for (int q = 0; q < 8; ++q) {
        int nc = q >> 2, c = q & 3;
        int col = nc * 64 + c * 16 + lm;
        __bf16 xb = __builtin_bit_cast(__bf16, (unsigned short)AX[rl * KS + col]);
        os[q] = a2[nc][c][r] + b2c[q] + (float)xb;
        sum += os[q];
      }
#pragma unroll
      for (int mm = 1; mm < 16; mm <<= 1) sum += __shfl_xor(sum, mm, 64);
      float mean = sum * (1.f / 128.f);
      float qv = 0.f;
#pragma unroll
      for (int q = 0; q < 8; ++q) { float dv = os[q] - mean; qv += dv * dv; }
#pragma unroll
      for (int mm = 1; mm < 16; mm <<= 1) qv += __shfl_xor(qv, mm, 64);
      float inv = rsqrtf(qv * (1.f / 128.f) + 1e-5f);
      float o[8];
#pragma unroll
      for (int q = 0; q < 8; ++q)
        o[q] = (os[q] - mean) * inv * g2c[q] + be2c[q];
      if (!last) {
        if (valid) {
#pragma unroll
          for (int q = 0; q < 8; ++q) {
            int col = (q >> 2) * 64 + (q & 3) * 16 + lm;
            U[(size_t)row * 128 + col] = o[q];
          }
        }
        // Ubf routed through AX (same elements this thread just read)
#pragma unroll
        for (int q = 0; q < 8; ++q) {
          int col = (q >> 2) * 64 + (q & 3) * 16 + lm;
          AX[rl * KS + col] = (short)__builtin_bit_cast(unsigned short, (__bf16)o[q]);
        }
      } else {
        float s2 = 0.f;
#pragma unroll
        for (int q = 0; q < 8; ++q) s2 += o[q];
#pragma unroll
        for (int mm = 1; mm < 16; mm <<= 1) s2 += __shfl_xor(s2, mm, 64);
        float mean2 = s2 * (1.f / 128.f);
        float qv2 = 0.f;
#pragma unroll
        for (int q = 0; q < 8; ++q) { float dv = o[q] - mean2; qv2 += dv * dv; }
#pragma unroll
        for (int mm = 1; mm < 16; mm <<= 1) qv2 += __shfl_xor(qv2, mm, 64);
        float inv2 = rsqrtf(qv2 * (1.f / 128.f) + 1e-5f);
        if (valid) {
          int bb = row / L;
          int t = row - bb * L;
          if (t < N * P) {
            int n = t >> 7, p = t & 127;
            size_t obase = (((size_t)bb * N + n) * D) * P + p;
#pragma unroll
            for (int q = 0; q < 8; ++q) {
              int col = (q >> 2) * 64 + (q & 3) * 16 + lm;
              float o2 = (o[q] - mean2) * inv2 * lnfg[col] + lnfb[col];
              outp[obase + (size_t)col * P] = o2;
            }
          }
        }
      }
    }
  }
  if (!last) {
    __syncthreads();
    // coalesced Ubf store from AX
#pragma unroll
    for (int i = 0; i < 4; ++i) {
      int rr = rr0 + 16 * i;
      int m = m0 + rr;
      if (m < BL)
        *(int4*)(Ubf + (size_t)m * 128 + gcol * 8) = *(const int4*)&AX[rr * KS + gcol * 8];
    }
  }
}

extern "C" void kernel_launch(void* const* d_in, const int* in_sizes, int n_in,
                              void* d_out, int out_size, void* d_ws, size_t ws_size,
                              hipStream_t stream)
{
  (void)in_sizes; (void)n_in; (void)out_size; (void)ws_size;
  const float* x       = (const float*)d_in[0];
  const float* view    = (const float*)d_in[1];
  const float* wp_w    = (const float*)d_in[2];
  const float* wp_b    = (const float*)d_in[3];
  const float* m_in_w  = (const float*)d_in[4];
  const float* m_conv_w= (const float*)d_in[5];
  const float* m_conv_b= (const float*)d_in[6];
  const float* m_xproj = (const float*)d_in[7];
  const float* m_dt_w  = (const float*)d_in[8];
  const float* m_dt_b  = (const float*)d_in[9];
  const float* m_Alog  = (const float*)d_in[10];
  const float* m_Dp    = (const float*)d_in[11];
  const float* m_out_w = (const float*)d_in[12];
  const float* ffn_w1  = (const float*)d_in[13];
  const float* ffn_b1  = (const float*)d_in[14];
  const float* ffn_w2  = (const float*)d_in[15];
  const float* ffn_b2  = (const float*)d_in[16];
  const float* ln1_g   = (const float*)d_in[17];
  const float* ln1_b   = (const float*)d_in[18];
  const float* ln2_g   = (const float*)d_in[19];
  const float* ln2_b   = (const float*)d_in[20];
  const float* lnf_g   = (const float*)d_in[21];
  const float* lnf_b   = (const float*)d_in[22];
  float* out = (float*)d_out;

  float* W = (float*)d_ws;
  size_t off = 0;
  auto alloc = [&](size_t nfl) { float* p = W + off; off += (nfl + 3) & ~(size_t)3; return p; };
  float* U      = alloc((size_t)BL * D);
  float* Ubf_f  = alloc((size_t)BL * D / 2);
  float* XCC_f  = alloc((size_t)BL * D);          // 2*BL*D bf16
  float* Zbf_f  = alloc((size_t)BL * D);          // 2*BL*D bf16
  float* DT_f   = alloc((size_t)BL * D);          // 2*BL*D bf16
  float* BCb    = alloc((size_t)2 * BL * 2 * DS);
  float* YM_f   = alloc((size_t)BL * 256 / 2);
  float* HC     = alloc((size_t)2 * B * NC * D * DS);
  float* DTS    = alloc((size_t)2 * B * NC * D);
  float* HIN    = alloc((size_t)2 * B * NC * D * DS);
  float* weff_f = alloc(262144 / 2);
  float* xpw_f  = alloc(20480 / 2);
  float* outw_f = alloc(65536 / 2);
  float* w1_f   = alloc(65536 / 2);
  float* w2_f   = alloc(65536 / 2);

  __bf16* Ubf    = (__bf16*)Ubf_f;
  __bf16* XCCbf  = (__bf16*)XCC_f;
  __bf16* Zbf    = (__bf16*)Zbf_f;
  __bf16* DTbf   = (__bf16*)DT_f;
  __bf16* YMbf   = (__bf16*)YM_f;
  __bf16* weff   = (__bf16*)weff_f;
  __bf16* xpw_bf = (__bf16*)xpw_f;
  __bf16* outw_bf= (__bf16*)outw_f;
  __bf16* w1_bf  = (__bf16*)w1_f;
  __bf16* w2_bf  = (__bf16*)w2_f;

  k_init<<<PREP_BLOCKS + EMBED_BLOCKS, 256, 0, stream>>>(
      m_in_w, m_conv_w, m_xproj, m_out_w, ffn_w1, ffn_w2,
      weff, xpw_bf, outw_bf, w1_bf, w2_bf,
      x, view, wp_w, wp_b, U, Ubf);

  for (int l = 0; l < EL; ++l) {
    const float* conv_b_l = m_conv_b + (size_t)l * 2 * D;
    const float* dt_w_l   = m_dt_w   + (size_t)l * 2 * D * DTR;
    const float* dt_b_l   = m_dt_b   + (size_t)l * 2 * D;
    const float* Alog_l   = m_Alog   + (size_t)l * 2 * D * DS;
    const float* Dp_l     = m_Dp     + (size_t)l * 2 * D;

    k_front <<<dim3(2 * MT64, 2), 256, 0, stream>>>(
        Ubf, weff + (size_t)l * 2 * 256 * 256, conv_b_l,
        xpw_bf + (size_t)l * 2 * 40 * 128, dt_w_l, dt_b_l,
        XCCbf, Zbf, BCb, DTbf);
    k_scanA <<<2 * B * NC, 128, 0, stream>>>(DTbf, XCCbf, BCb, Alog_l, HC, DTS);
    k_scanB <<<2 * B * 16, 128, 0, stream>>>(HC, DTS, Alog_l, HIN);
    k_scanC <<<2 * B * NC, 128, 0, stream>>>(DTbf, XCCbf, BCb, Zbf, HIN, Alog_l, Dp_l, YMbf);
    k_tail  <<<MT64, 256, 0, stream>>>(
        YMbf, outw_bf + (size_t)l * 128 * 256,
        ln1_g + l * D, ln1_b + l * D,
        w1_bf + (size_t)l * 256 * 128, ffn_b1 + l * DFF,
        w2_bf + (size_t)l * 128 * 256, ffn_b2 + l * D,
        ln2_g + l * D, ln2_b + l * D, U, Ubf,
        (l == EL - 1) ? 1 : 0, lnf_g, lnf_b, out);
  }
}